// Round 8
// baseline (218.465 us; speedup 1.0000x reference)
//
#include <hip/hip_runtime.h>

#define T_SEQ 4096
#define DM    768
#define NH    12
#define DH    64
#define NC    2304   // 3 * DM

using half8  = __attribute__((ext_vector_type(8))) _Float16;
using half4v = __attribute__((ext_vector_type(4))) _Float16;
using f32x4  = __attribute__((ext_vector_type(4))) float;
using f32x16 = __attribute__((ext_vector_type(16))) float;
typedef unsigned int u32;

union H8 { half8 v; u32 u[4]; };

// cvt_pkrtz returns __fp16 ext_vector(2); bit-cast straight to u32.
__device__ __forceinline__ u32 pkrtz_u32(float a, float b) {
    return __builtin_bit_cast(u32, __builtin_amdgcn_cvt_pkrtz(a, b));
}
__device__ __forceinline__ float asf(u32 x) { return __builtin_bit_cast(float, x); }
__device__ __forceinline__ u32 asu(float x) { return __builtin_bit_cast(u32, x); }

__device__ __forceinline__ void async_copy16(void* lds, const void* g) {
    __builtin_amdgcn_global_load_lds(
        (const __attribute__((address_space(1))) u32*)g,
        (__attribute__((address_space(3))) u32*)lds, 16, 0, 0);
}

// ---------------------------------------------------------------------------
// x (fp32) -> xh (fp16)
// ---------------------------------------------------------------------------
__global__ __launch_bounds__(256)
void convert_x_kernel(const float* __restrict__ x, _Float16* __restrict__ xh) {
    const size_t i = ((size_t)blockIdx.x * 256 + threadIdx.x) * 8;
    float4 a = *(const float4*)(x + i);
    float4 b = *(const float4*)(x + i + 4);
    half8 o = { (_Float16)a.x, (_Float16)a.y, (_Float16)a.z, (_Float16)a.w,
                (_Float16)b.x, (_Float16)b.y, (_Float16)b.z, (_Float16)b.w };
    *(half8*)(xh + i) = o;
}

// ---------------------------------------------------------------------------
// src [R][C] fp32 -> dst [C][R] fp16 (weight transpose+convert)
// ---------------------------------------------------------------------------
__global__ __launch_bounds__(256)
void transpose_convert_kernel(const float* __restrict__ src,
                              _Float16* __restrict__ dst, int R, int C) {
    __shared__ _Float16 tile[64][72];
    const int tid = threadIdx.x;
    const int tc0 = blockIdx.x * 64;
    const int tr0 = blockIdx.y * 64;
    const int r = tid >> 2, c4 = (tid & 3) * 16;
    const float* sp = src + (size_t)(tr0 + r) * C + tc0 + c4;
    #pragma unroll
    for (int j = 0; j < 16; j += 4) {
        float4 t4 = *(const float4*)(sp + j);
        tile[r][c4 + j + 0] = (_Float16)t4.x;
        tile[r][c4 + j + 1] = (_Float16)t4.y;
        tile[r][c4 + j + 2] = (_Float16)t4.z;
        tile[r][c4 + j + 3] = (_Float16)t4.w;
    }
    __syncthreads();
    const int c = tid >> 2, r4 = (tid & 3) * 16;
    half8 o0, o1;
    #pragma unroll
    for (int j = 0; j < 8; ++j) o0[j] = tile[r4 + j][c];
    #pragma unroll
    for (int j = 0; j < 8; ++j) o1[j] = tile[r4 + 8 + j][c];
    _Float16* dp = dst + (size_t)(tc0 + c) * R + tr0 + r4;
    *(half8*)(dp) = o0;
    *(half8*)(dp + 8) = o1;
}

// ---------------------------------------------------------------------------
// fp16 MFMA GEMM (m97 structure)
// ---------------------------------------------------------------------------
__global__ __launch_bounds__(256, 2)
void qkv_mfma_kernel(const _Float16* __restrict__ A,
                     const _Float16* __restrict__ Bt,
                     _Float16* __restrict__ q, _Float16* __restrict__ k,
                     _Float16* __restrict__ v) {
    __shared__ _Float16 Alds[128 * 64];
    __shared__ _Float16 Blds[128 * 64];
    const int tid  = threadIdx.x;
    const int lane = tid & 63;
    const int w    = tid >> 6;
    const int wr = w >> 1, wc = w & 1;
    const int lrow = lane >> 4, lcol = lane & 15;

    const int bid  = blockIdx.x;                    // 576 = 8 * 72
    const int virt = (bid & 7) * 72 + (bid >> 3);
    const int cbn  = virt % 18, rbn = virt / 18;

    const _Float16* Ag = A  + (size_t)rbn * 128 * DM;
    const _Float16* Bg = Bt + (size_t)cbn * 128 * DM;

    int srow[4], scol[4];
    #pragma unroll
    for (int i = 0; i < 4; ++i) {
        const int idx = i * 256 + tid;
        srow[i] = idx >> 3;
        scol[i] = ((idx & 7) ^ (srow[i] & 7)) * 8;
    }

    f32x4 acc[4][4];
    #pragma unroll
    for (int mf = 0; mf < 4; ++mf)
        #pragma unroll
        for (int nf = 0; nf < 4; ++nf) acc[mf][nf] = (f32x4){0.f, 0.f, 0.f, 0.f};

    for (int kt = 0; kt < DM / 64; ++kt) {
        const int k0 = kt * 64;
        __syncthreads();
        #pragma unroll
        for (int i = 0; i < 4; ++i) {
            async_copy16((char*)Alds + (i * 256 + w * 64) * 16,
                         Ag + (size_t)srow[i] * DM + k0 + scol[i]);
            async_copy16((char*)Blds + (i * 256 + w * 64) * 16,
                         Bg + (size_t)srow[i] * DM + k0 + scol[i]);
        }
        __syncthreads();
        #pragma unroll
        for (int kh = 0; kh < 2; ++kh) {
            half8 af[4], bf[4];
            const int ag = kh * 4 + lrow;
            #pragma unroll
            for (int f = 0; f < 4; ++f) {
                const int ar = wr * 64 + f * 16 + lcol;
                af[f] = *(const half8*)((const char*)Alds +
                          ar * 128 + ((ag ^ (ar & 7)) << 4));
                const int br = wc * 64 + f * 16 + lcol;
                bf[f] = *(const half8*)((const char*)Blds +
                          br * 128 + ((ag ^ (br & 7)) << 4));
            }
            #pragma unroll
            for (int mf = 0; mf < 4; ++mf)
                #pragma unroll
                for (int nf = 0; nf < 4; ++nf)
                    acc[mf][nf] = __builtin_amdgcn_mfma_f32_16x16x32_f16(
                        af[mf], bf[nf], acc[mf][nf], 0, 0, 0);
        }
    }

    #pragma unroll
    for (int nf = 0; nf < 4; ++nf) {
        const int n = cbn * 128 + wc * 64 + nf * 16 + lcol;
        const int head  = n / 192;
        const int which = (n >> 6) % 3;
        const int d = n & 63;
        _Float16* dst = (which == 0) ? q : (which == 1) ? k : v;
        const float sc = (which == 0) ? 0.18033688011112042f : 1.0f;
        dst += (size_t)head * T_SEQ * DH + d;
        #pragma unroll
        for (int mf = 0; mf < 4; ++mf) {
            const int t0 = rbn * 128 + wr * 64 + mf * 16 + lrow * 4;
            #pragma unroll
            for (int r = 0; r < 4; ++r)
                dst[(size_t)(t0 + r) * DH] = (_Float16)(acc[mf][nf][r] * sc);
        }
    }
}

__global__ __launch_bounds__(256, 2)
void proj_mfma_kernel(const _Float16* __restrict__ A,
                      const _Float16* __restrict__ Bt,
                      const float* __restrict__ bias, float* __restrict__ out) {
    __shared__ _Float16 Alds[128 * 64];
    __shared__ _Float16 Blds[128 * 64];
    const int tid  = threadIdx.x;
    const int lane = tid & 63;
    const int w    = tid >> 6;
    const int wr = w >> 1, wc = w & 1;
    const int lrow = lane >> 4, lcol = lane & 15;

    const int bid  = blockIdx.x;                    // 192 = 8 * 24
    const int virt = (bid & 7) * 24 + (bid >> 3);
    const int cbn  = virt % 6, rbn = virt / 6;

    const _Float16* Ag = A  + (size_t)rbn * 128 * DM;
    const _Float16* Bg = Bt + (size_t)cbn * 128 * DM;

    int srow[4], scol[4];
    #pragma unroll
    for (int i = 0; i < 4; ++i) {
        const int idx = i * 256 + tid;
        srow[i] = idx >> 3;
        scol[i] = ((idx & 7) ^ (srow[i] & 7)) * 8;
    }

    f32x4 acc[4][4];
    #pragma unroll
    for (int mf = 0; mf < 4; ++mf)
        #pragma unroll
        for (int nf = 0; nf < 4; ++nf) acc[mf][nf] = (f32x4){0.f, 0.f, 0.f, 0.f};

    for (int kt = 0; kt < DM / 64; ++kt) {
        const int k0 = kt * 64;
        __syncthreads();
        #pragma unroll
        for (int i = 0; i < 4; ++i) {
            async_copy16((char*)Alds + (i * 256 + w * 64) * 16,
                         Ag + (size_t)srow[i] * DM + k0 + scol[i]);
            async_copy16((char*)Blds + (i * 256 + w * 64) * 16,
                         Bg + (size_t)srow[i] * DM + k0 + scol[i]);
        }
        __syncthreads();
        #pragma unroll
        for (int kh = 0; kh < 2; ++kh) {
            half8 af[4], bf[4];
            const int ag = kh * 4 + lrow;
            #pragma unroll
            for (int f = 0; f < 4; ++f) {
                const int ar = wr * 64 + f * 16 + lcol;
                af[f] = *(const half8*)((const char*)Alds +
                          ar * 128 + ((ag ^ (ar & 7)) << 4));
                const int br = wc * 64 + f * 16 + lcol;
                bf[f] = *(const half8*)((const char*)Blds +
                          br * 128 + ((ag ^ (br & 7)) << 4));
            }
            #pragma unroll
            for (int mf = 0; mf < 4; ++mf)
                #pragma unroll
                for (int nf = 0; nf < 4; ++nf)
                    acc[mf][nf] = __builtin_amdgcn_mfma_f32_16x16x32_f16(
                        af[mf], bf[nf], acc[mf][nf], 0, 0, 0);
        }
    }

    #pragma unroll
    for (int nf = 0; nf < 4; ++nf) {
        const int n = cbn * 128 + wc * 64 + nf * 16 + lcol;
        const float b = bias[n];
        #pragma unroll
        for (int mf = 0; mf < 4; ++mf) {
            const int t0 = rbn * 128 + wr * 64 + mf * 16 + lrow * 4;
            #pragma unroll
            for (int r = 0; r < 4; ++r)
                out[(size_t)(t0 + r) * DM + n] = acc[mf][nf][r] + b;
        }
    }
}

// ---------------------------------------------------------------------------
// V [h][t][d] -> Vt [h][d][t] (fp16)
// ---------------------------------------------------------------------------
__global__ __launch_bounds__(256)
void vt_kernel(const _Float16* __restrict__ v, _Float16* __restrict__ vt) {
    __shared__ _Float16 tile[64][65];
    const int tid = threadIdx.x;
    const int tb = blockIdx.x, h = blockIdx.y;
    const int r = tid >> 2, c0 = (tid & 3) * 16;
    const _Float16* src = v + ((size_t)h * T_SEQ + tb * 64 + r) * 64 + c0;
    half8 a0 = *(const half8*)(src);
    half8 a1 = *(const half8*)(src + 8);
    #pragma unroll
    for (int j = 0; j < 8; ++j) tile[r][c0 + j] = a0[j];
    #pragma unroll
    for (int j = 0; j < 8; ++j) tile[r][c0 + 8 + j] = a1[j];
    __syncthreads();
    const int d = tid >> 2, t0 = (tid & 3) * 16;
    half8 o0, o1;
    #pragma unroll
    for (int j = 0; j < 8; ++j) o0[j] = tile[t0 + j][d];
    #pragma unroll
    for (int j = 0; j < 8; ++j) o1[j] = tile[t0 + 8 + j][d];
    _Float16* dst = vt + ((size_t)h * 64 + d) * T_SEQ + tb * 64 + t0;
    *(half8*)(dst) = o0;
    *(half8*)(dst + 8) = o1;
}

// ---------------------------------------------------------------------------
// Flash attention, swapped-operand 32x32x16 MFMA, zero LDS / zero barriers.
// Round 8: XCD-AWARE work mapping (T1). Previous h = bid%12 with XCD=bid%8
// spread all 12 heads across every XCD -> per-XCD K/V footprint 12.6 MB >>
// 4 MB L2 -> every fragment load was an L2 miss (~1-2k cyc) that prefetch
// couldn't cover; that was the ~4900 cyc/iter. Now each XCD owns a
// contiguous 1.5-head slice (<=2 heads = 2.1 MB K+V -> L2-resident), and
// within the slice heavy/light chunks interleave so co-resident waves on a
// SIMD pair ~64+~1 iterations (load balance).
// ---------------------------------------------------------------------------
__global__ __launch_bounds__(64)
void attn_mfma32_kernel(const _Float16* __restrict__ qg,
                        const _Float16* __restrict__ kg,
                        const _Float16* __restrict__ vtg,
                        _Float16* __restrict__ att) {
    const int lane = threadIdx.x & 63;
    const int l31  = lane & 31;
    const int hi   = lane >> 5;

    // XCD-aware: xcd = bid&7 (1536%8==0, bijective); each XCD gets a
    // contiguous 192-work slice = 1.5 heads. j interleaves heavy/light.
    const int bid = blockIdx.x;
    const int w_  = (bid & 7) * 192 + (bid >> 3);
    const int h   = w_ >> 7;             // w_/128: 0..11
    const int j   = w_ & 127;
    const int c   = (j & 1) ? (j >> 1) : (127 - (j >> 1));
    const int q0  = c * 32;
    const int q   = q0 + l31;            // this lane's q-row
    const int niter = c / 2 + 1;
    const int maxkvb = (niter - 1) * 64;

    const _Float16* Qh = qg  + ((size_t)h * T_SEQ + q) * DH;
    const _Float16* Kh = kg  + (size_t)h * T_SEQ * DH;
    const _Float16* Vh = vtg + (size_t)h * DH * T_SEQ;

    // Q fragments (B operand): col=lane&31=q, k(d) = 16*ks + hi*8 + j
    half8 qf[4];
    #pragma unroll
    for (int ks = 0; ks < 4; ++ks)
        qf[ks] = *(const half8*)(Qh + ks * 16 + hi * 8);

    f32x16 o0v = {}, o1v = {};           // O^T d-tiles 0..31, 32..63
    float m = -1e30f, l = 0.f;

    // K buffers: [0..3] = rows kvb+l31 (tile A), [4..7] = rows kvb+32+l31 (B)
    half8 kbuf0[8], kbuf1[8];
    #pragma unroll
    for (int ks = 0; ks < 4; ++ks) {
        kbuf0[ks]     = *(const half8*)(Kh + (size_t)l31 * DH + ks * 16 + hi * 8);
        kbuf0[4 + ks] = *(const half8*)(Kh + (size_t)(32 + l31) * DH + ks * 16 + hi * 8);
    }

    auto body = [&](int it, half8* kc, half8* kn) {
        const int kvb = it * 64;
        const int nkvb = (kvb + 64 <= maxkvb) ? kvb + 64 : maxkvb;  // clamp

        // ---- prefetch next K tile (in flight during S-MFMA + softmax)
        #pragma unroll
        for (int ks = 0; ks < 4; ++ks) {
            kn[ks]     = *(const half8*)(Kh + (size_t)(nkvb + l31) * DH + ks * 16 + hi * 8);
            kn[4 + ks] = *(const half8*)(Kh + (size_t)(nkvb + 32 + l31) * DH + ks * 16 + hi * 8);
        }
        // ---- V^T frags (A operand): row=lane&31=d, k(kv)=16ks2+hi*8+j
        half8 vf[2][2][2];   // [kv-tile][dt][ks2]
        #pragma unroll
        for (int t = 0; t < 2; ++t)
            #pragma unroll
            for (int dt = 0; dt < 2; ++dt)
                #pragma unroll
                for (int ks2 = 0; ks2 < 2; ++ks2)
                    vf[t][dt][ks2] = *(const half8*)(Vh +
                        (size_t)(dt * 32 + l31) * T_SEQ +
                        kvb + t * 32 + ks2 * 16 + hi * 8);

        // ---- S^T = K Q^T
        f32x16 sA = {}, sB = {};
        __builtin_amdgcn_s_setprio(1);
        #pragma unroll
        for (int ks = 0; ks < 4; ++ks) {
            sA = __builtin_amdgcn_mfma_f32_32x32x16_f16(kc[ks],     qf[ks], sA, 0, 0, 0);
            sB = __builtin_amdgcn_mfma_f32_32x32x16_f16(kc[4 + ks], qf[ks], sB, 0, 0, 0);
        }
        __builtin_amdgcn_s_setprio(0);

        // ---- causal mask (last iteration only)
        if (it == niter - 1) {
            #pragma unroll
            for (int r = 0; r < 16; ++r) {
                const int off = (r & 3) + 8 * (r >> 2) + 4 * hi;
                if (kvb + off > q)      sA[r] = -1e30f;
                if (kvb + 32 + off > q) sB[r] = -1e30f;
            }
        }

        // ---- online softmax (exp2 domain): tree max, permlane cross-half
        float t8[8];
        #pragma unroll
        for (int r = 0; r < 8; ++r)
            t8[r] = fmaxf(fmaxf(sA[r], sA[r + 8]), fmaxf(sB[r], sB[r + 8]));
        float t4a = fmaxf(t8[0], t8[4]), t4b = fmaxf(t8[1], t8[5]);
        float t4c = fmaxf(t8[2], t8[6]), t4d = fmaxf(t8[3], t8[7]);
        float pmax = fmaxf(fmaxf(t4a, t4b), fmaxf(t4c, t4d));
        {
            auto r = __builtin_amdgcn_permlane32_swap(asu(pmax), asu(pmax), false, false);
            pmax = fmaxf(asf(r[0]), asf(r[1]));
        }

        if (!__all(pmax - m <= 11.0f)) {   // defer-max: skip rescale if small
            const float mnew = fmaxf(m, pmax);
            const float alpha = exp2f(m - mnew);
            m = mnew;
            l *= alpha;
            #pragma unroll
            for (int r = 0; r < 16; ++r) { o0v[r] *= alpha; o1v[r] *= alpha; }
        }
        #pragma unroll
        for (int r = 0; r < 16; ++r) sA[r] = exp2f(sA[r] - m);
        #pragma unroll
        for (int r = 0; r < 16; ++r) sB[r] = exp2f(sB[r] - m);
        float s8[8];
        #pragma unroll
        for (int r = 0; r < 8; ++r)
            s8[r] = (sA[r] + sA[r + 8]) + (sB[r] + sB[r + 8]);
        float rsum = ((s8[0] + s8[4]) + (s8[1] + s8[5])) +
                     ((s8[2] + s8[6]) + (s8[3] + s8[7]));
        {
            auto r = __builtin_amdgcn_permlane32_swap(asu(rsum), asu(rsum), false, false);
            rsum = asf(r[0]) + asf(r[1]);
        }
        l += rsum;

        // ---- pack P -> PV B-frags: 4 cvt_pkrtz + 2 permlane per group
        H8 pfA[2], pfB[2];
        #pragma unroll
        for (int ks2 = 0; ks2 < 2; ++ks2) {
            {
                const u32 a0 = pkrtz_u32(sA[8*ks2+0], sA[8*ks2+1]);
                const u32 a1 = pkrtz_u32(sA[8*ks2+2], sA[8*ks2+3]);
                const u32 b0 = pkrtz_u32(sA[8*ks2+4], sA[8*ks2+5]);
                const u32 b1 = pkrtz_u32(sA[8*ks2+6], sA[8*ks2+7]);
                auto r0 = __builtin_amdgcn_permlane32_swap(a0, b0, false, false);
                auto r1 = __builtin_amdgcn_permlane32_swap(a1, b1, false, false);
                pfA[ks2].u[0] = r0[0];
                pfA[ks2].u[1] = r1[0];
                pfA[ks2].u[2] = r0[1];
                pfA[ks2].u[3] = r1[1];
            }
            {
                const u32 a0 = pkrtz_u32(sB[8*ks2+0], sB[8*ks2+1]);
                const u32 a1 = pkrtz_u32(sB[8*ks2+2], sB[8*ks2+3]);
                const u32 b0 = pkrtz_u32(sB[8*ks2+4], sB[8*ks2+5]);
                const u32 b1 = pkrtz_u32(sB[8*ks2+6], sB[8*ks2+7]);
                auto r0 = __builtin_amdgcn_permlane32_swap(a0, b0, false, false);
                auto r1 = __builtin_amdgcn_permlane32_swap(a1, b1, false, false);
                pfB[ks2].u[0] = r0[0];
                pfB[ks2].u[1] = r1[0];
                pfB[ks2].u[2] = r0[1];
                pfB[ks2].u[3] = r1[1];
            }
        }

        // ---- PV: O^T[d][q] += V^T · P̂
        __builtin_amdgcn_s_setprio(1);
        #pragma unroll
        for (int ks2 = 0; ks2 < 2; ++ks2) {
            o0v = __builtin_amdgcn_mfma_f32_32x32x16_f16(vf[0][0][ks2], pfA[ks2].v, o0v, 0, 0, 0);
            o1v = __builtin_amdgcn_mfma_f32_32x32x16_f16(vf[0][1][ks2], pfA[ks2].v, o1v, 0, 0, 0);
            o0v = __builtin_amdgcn_mfma_f32_32x32x16_f16(vf[1][0][ks2], pfB[ks2].v, o0v, 0, 0, 0);
            o1v = __builtin_amdgcn_mfma_f32_32x32x16_f16(vf[1][1][ks2], pfB[ks2].v, o1v, 0, 0, 0);
        }
        __builtin_amdgcn_s_setprio(0);
    };

    // 2x-unrolled ping-pong so buffer indices stay compile-time (rule #20)
    int it = 0;
    while (true) {
        body(it, kbuf0, kbuf1);
        if (++it >= niter) break;
        body(it, kbuf1, kbuf0);
        if (++it >= niter) break;
    }

    // ---- epilogue: O^T[d][q] -> att[q][h*64+d], normalize by l
    const float inv = 1.0f / l;
    _Float16* ap = att + (size_t)q * DM + h * DH + 4 * hi;
    #pragma unroll
    for (int g = 0; g < 4; ++g) {
        half4v w0 = { (_Float16)(o0v[4*g+0] * inv), (_Float16)(o0v[4*g+1] * inv),
                      (_Float16)(o0v[4*g+2] * inv), (_Float16)(o0v[4*g+3] * inv) };
        half4v w1 = { (_Float16)(o1v[4*g+0] * inv), (_Float16)(o1v[4*g+1] * inv),
                      (_Float16)(o1v[4*g+2] * inv), (_Float16)(o1v[4*g+3] * inv) };
        *(half4v*)(ap + 8 * g)      = w0;
        *(half4v*)(ap + 32 + 8 * g) = w1;
    }
}

// ---------------------------------------------------------------------------
extern "C" void kernel_launch(void* const* d_in, const int* in_sizes, int n_in,
                              void* d_out, int out_size, void* d_ws, size_t ws_size,
                              hipStream_t stream) {
    const float* x      = (const float*)d_in[0];
    const float* w_qkv  = (const float*)d_in[1];
    const float* w_proj = (const float*)d_in[2];
    const float* b_proj = (const float*)d_in[3];
    float* out = (float*)d_out;

    _Float16* wsb = (_Float16*)d_ws;
    const size_t XS = (size_t)T_SEQ * DM;
    const size_t HS = (size_t)NH * T_SEQ * DH;
    _Float16* xh     = wsb;
    _Float16* wqkvT  = xh + XS;
    _Float16* wprojT = wqkvT + (size_t)NC * DM;
    _Float16* q      = wprojT + (size_t)DM * DM;
    _Float16* k      = q + HS;
    _Float16* v      = k + HS;
    _Float16* vt     = v + HS;
    _Float16* att    = vt + HS;

    convert_x_kernel<<<dim3(1536), 256, 0, stream>>>(x, xh);
    transpose_convert_kernel<<<dim3(36, 12), 256, 0, stream>>>(w_qkv, wqkvT, DM, NC);
    transpose_convert_kernel<<<dim3(12, 12), 256, 0, stream>>>(w_proj, wprojT, DM, DM);
    qkv_mfma_kernel<<<dim3(576), 256, 0, stream>>>(xh, wqkvT, q, k, v);
    vt_kernel<<<dim3(64, NH), 256, 0, stream>>>(v, vt);
    attn_mfma32_kernel<<<dim3(1536), 64, 0, stream>>>(q, k, vt, att);
    proj_mfma_kernel<<<dim3(192), 256, 0, stream>>>(att, wprojT, b_proj, out);
}

// Round 9
// 175.984 us; speedup vs baseline: 1.2414x; 1.2414x over previous
//
#include <hip/hip_runtime.h>

#define T_SEQ 4096
#define DM    768
#define NH    12
#define DH    64
#define NC    2304   // 3 * DM

using half8  = __attribute__((ext_vector_type(8))) _Float16;
using half4v = __attribute__((ext_vector_type(4))) _Float16;
using f32x4  = __attribute__((ext_vector_type(4))) float;
using f32x16 = __attribute__((ext_vector_type(16))) float;
typedef unsigned int u32;

union H8 { half8 v; u32 u[4]; };

// cvt_pkrtz returns __fp16 ext_vector(2); bit-cast straight to u32.
__device__ __forceinline__ u32 pkrtz_u32(float a, float b) {
    return __builtin_bit_cast(u32, __builtin_amdgcn_cvt_pkrtz(a, b));
}
__device__ __forceinline__ float asf(u32 x) { return __builtin_bit_cast(float, x); }
__device__ __forceinline__ u32 asu(float x) { return __builtin_bit_cast(u32, x); }

__device__ __forceinline__ void async_copy16(void* lds, const void* g) {
    __builtin_amdgcn_global_load_lds(
        (const __attribute__((address_space(1))) u32*)g,
        (__attribute__((address_space(3))) u32*)lds, 16, 0, 0);
}

// ---------------------------------------------------------------------------
// x (fp32) -> xh (fp16)
// ---------------------------------------------------------------------------
__global__ __launch_bounds__(256)
void convert_x_kernel(const float* __restrict__ x, _Float16* __restrict__ xh) {
    const size_t i = ((size_t)blockIdx.x * 256 + threadIdx.x) * 8;
    float4 a = *(const float4*)(x + i);
    float4 b = *(const float4*)(x + i + 4);
    half8 o = { (_Float16)a.x, (_Float16)a.y, (_Float16)a.z, (_Float16)a.w,
                (_Float16)b.x, (_Float16)b.y, (_Float16)b.z, (_Float16)b.w };
    *(half8*)(xh + i) = o;
}

// ---------------------------------------------------------------------------
// src [R][C] fp32 -> dst [C][R] fp16 (weight transpose+convert)
// ---------------------------------------------------------------------------
__global__ __launch_bounds__(256)
void transpose_convert_kernel(const float* __restrict__ src,
                              _Float16* __restrict__ dst, int R, int C) {
    __shared__ _Float16 tile[64][72];
    const int tid = threadIdx.x;
    const int tc0 = blockIdx.x * 64;
    const int tr0 = blockIdx.y * 64;
    const int r = tid >> 2, c4 = (tid & 3) * 16;
    const float* sp = src + (size_t)(tr0 + r) * C + tc0 + c4;
    #pragma unroll
    for (int j = 0; j < 16; j += 4) {
        float4 t4 = *(const float4*)(sp + j);
        tile[r][c4 + j + 0] = (_Float16)t4.x;
        tile[r][c4 + j + 1] = (_Float16)t4.y;
        tile[r][c4 + j + 2] = (_Float16)t4.z;
        tile[r][c4 + j + 3] = (_Float16)t4.w;
    }
    __syncthreads();
    const int c = tid >> 2, r4 = (tid & 3) * 16;
    half8 o0, o1;
    #pragma unroll
    for (int j = 0; j < 8; ++j) o0[j] = tile[r4 + j][c];
    #pragma unroll
    for (int j = 0; j < 8; ++j) o1[j] = tile[r4 + 8 + j][c];
    _Float16* dp = dst + (size_t)(tc0 + c) * R + tr0 + r4;
    *(half8*)(dp) = o0;
    *(half8*)(dp + 8) = o1;
}

// ---------------------------------------------------------------------------
// fp16 MFMA GEMM (m97 structure)
// ---------------------------------------------------------------------------
__global__ __launch_bounds__(256, 2)
void qkv_mfma_kernel(const _Float16* __restrict__ A,
                     const _Float16* __restrict__ Bt,
                     _Float16* __restrict__ q, _Float16* __restrict__ k,
                     _Float16* __restrict__ v) {
    __shared__ _Float16 Alds[128 * 64];
    __shared__ _Float16 Blds[128 * 64];
    const int tid  = threadIdx.x;
    const int lane = tid & 63;
    const int w    = tid >> 6;
    const int wr = w >> 1, wc = w & 1;
    const int lrow = lane >> 4, lcol = lane & 15;

    const int bid  = blockIdx.x;                    // 576 = 8 * 72
    const int virt = (bid & 7) * 72 + (bid >> 3);
    const int cbn  = virt % 18, rbn = virt / 18;

    const _Float16* Ag = A  + (size_t)rbn * 128 * DM;
    const _Float16* Bg = Bt + (size_t)cbn * 128 * DM;

    int srow[4], scol[4];
    #pragma unroll
    for (int i = 0; i < 4; ++i) {
        const int idx = i * 256 + tid;
        srow[i] = idx >> 3;
        scol[i] = ((idx & 7) ^ (srow[i] & 7)) * 8;
    }

    f32x4 acc[4][4];
    #pragma unroll
    for (int mf = 0; mf < 4; ++mf)
        #pragma unroll
        for (int nf = 0; nf < 4; ++nf) acc[mf][nf] = (f32x4){0.f, 0.f, 0.f, 0.f};

    for (int kt = 0; kt < DM / 64; ++kt) {
        const int k0 = kt * 64;
        __syncthreads();
        #pragma unroll
        for (int i = 0; i < 4; ++i) {
            async_copy16((char*)Alds + (i * 256 + w * 64) * 16,
                         Ag + (size_t)srow[i] * DM + k0 + scol[i]);
            async_copy16((char*)Blds + (i * 256 + w * 64) * 16,
                         Bg + (size_t)srow[i] * DM + k0 + scol[i]);
        }
        __syncthreads();
        #pragma unroll
        for (int kh = 0; kh < 2; ++kh) {
            half8 af[4], bf[4];
            const int ag = kh * 4 + lrow;
            #pragma unroll
            for (int f = 0; f < 4; ++f) {
                const int ar = wr * 64 + f * 16 + lcol;
                af[f] = *(const half8*)((const char*)Alds +
                          ar * 128 + ((ag ^ (ar & 7)) << 4));
                const int br = wc * 64 + f * 16 + lcol;
                bf[f] = *(const half8*)((const char*)Blds +
                          br * 128 + ((ag ^ (br & 7)) << 4));
            }
            #pragma unroll
            for (int mf = 0; mf < 4; ++mf)
                #pragma unroll
                for (int nf = 0; nf < 4; ++nf)
                    acc[mf][nf] = __builtin_amdgcn_mfma_f32_16x16x32_f16(
                        af[mf], bf[nf], acc[mf][nf], 0, 0, 0);
        }
    }

    #pragma unroll
    for (int nf = 0; nf < 4; ++nf) {
        const int n = cbn * 128 + wc * 64 + nf * 16 + lcol;
        const int head  = n / 192;
        const int which = (n >> 6) % 3;
        const int d = n & 63;
        _Float16* dst = (which == 0) ? q : (which == 1) ? k : v;
        const float sc = (which == 0) ? 0.18033688011112042f : 1.0f;
        dst += (size_t)head * T_SEQ * DH + d;
        #pragma unroll
        for (int mf = 0; mf < 4; ++mf) {
            const int t0 = rbn * 128 + wr * 64 + mf * 16 + lrow * 4;
            #pragma unroll
            for (int r = 0; r < 4; ++r)
                dst[(size_t)(t0 + r) * DH] = (_Float16)(acc[mf][nf][r] * sc);
        }
    }
}

__global__ __launch_bounds__(256, 2)
void proj_mfma_kernel(const _Float16* __restrict__ A,
                      const _Float16* __restrict__ Bt,
                      const float* __restrict__ bias, float* __restrict__ out) {
    __shared__ _Float16 Alds[128 * 64];
    __shared__ _Float16 Blds[128 * 64];
    const int tid  = threadIdx.x;
    const int lane = tid & 63;
    const int w    = tid >> 6;
    const int wr = w >> 1, wc = w & 1;
    const int lrow = lane >> 4, lcol = lane & 15;

    const int bid  = blockIdx.x;                    // 192 = 8 * 24
    const int virt = (bid & 7) * 24 + (bid >> 3);
    const int cbn  = virt % 6, rbn = virt / 6;

    const _Float16* Ag = A  + (size_t)rbn * 128 * DM;
    const _Float16* Bg = Bt + (size_t)cbn * 128 * DM;

    int srow[4], scol[4];
    #pragma unroll
    for (int i = 0; i < 4; ++i) {
        const int idx = i * 256 + tid;
        srow[i] = idx >> 3;
        scol[i] = ((idx & 7) ^ (srow[i] & 7)) * 8;
    }

    f32x4 acc[4][4];
    #pragma unroll
    for (int mf = 0; mf < 4; ++mf)
        #pragma unroll
        for (int nf = 0; nf < 4; ++nf) acc[mf][nf] = (f32x4){0.f, 0.f, 0.f, 0.f};

    for (int kt = 0; kt < DM / 64; ++kt) {
        const int k0 = kt * 64;
        __syncthreads();
        #pragma unroll
        for (int i = 0; i < 4; ++i) {
            async_copy16((char*)Alds + (i * 256 + w * 64) * 16,
                         Ag + (size_t)srow[i] * DM + k0 + scol[i]);
            async_copy16((char*)Blds + (i * 256 + w * 64) * 16,
                         Bg + (size_t)srow[i] * DM + k0 + scol[i]);
        }
        __syncthreads();
        #pragma unroll
        for (int kh = 0; kh < 2; ++kh) {
            half8 af[4], bf[4];
            const int ag = kh * 4 + lrow;
            #pragma unroll
            for (int f = 0; f < 4; ++f) {
                const int ar = wr * 64 + f * 16 + lcol;
                af[f] = *(const half8*)((const char*)Alds +
                          ar * 128 + ((ag ^ (ar & 7)) << 4));
                const int br = wc * 64 + f * 16 + lcol;
                bf[f] = *(const half8*)((const char*)Blds +
                          br * 128 + ((ag ^ (br & 7)) << 4));
            }
            #pragma unroll
            for (int mf = 0; mf < 4; ++mf)
                #pragma unroll
                for (int nf = 0; nf < 4; ++nf)
                    acc[mf][nf] = __builtin_amdgcn_mfma_f32_16x16x32_f16(
                        af[mf], bf[nf], acc[mf][nf], 0, 0, 0);
        }
    }

    #pragma unroll
    for (int nf = 0; nf < 4; ++nf) {
        const int n = cbn * 128 + wc * 64 + nf * 16 + lcol;
        const float b = bias[n];
        #pragma unroll
        for (int mf = 0; mf < 4; ++mf) {
            const int t0 = rbn * 128 + wr * 64 + mf * 16 + lrow * 4;
            #pragma unroll
            for (int r = 0; r < 4; ++r)
                out[(size_t)(t0 + r) * DM + n] = acc[mf][nf][r] + b;
        }
    }
}

// ---------------------------------------------------------------------------
// V [h][t][d] -> Vt [h][d][t] (fp16)
// ---------------------------------------------------------------------------
__global__ __launch_bounds__(256)
void vt_kernel(const _Float16* __restrict__ v, _Float16* __restrict__ vt) {
    __shared__ _Float16 tile[64][65];
    const int tid = threadIdx.x;
    const int tb = blockIdx.x, h = blockIdx.y;
    const int r = tid >> 2, c0 = (tid & 3) * 16;
    const _Float16* src = v + ((size_t)h * T_SEQ + tb * 64 + r) * 64 + c0;
    half8 a0 = *(const half8*)(src);
    half8 a1 = *(const half8*)(src + 8);
    #pragma unroll
    for (int j = 0; j < 8; ++j) tile[r][c0 + j] = a0[j];
    #pragma unroll
    for (int j = 0; j < 8; ++j) tile[r][c0 + 8 + j] = a1[j];
    __syncthreads();
    const int d = tid >> 2, t0 = (tid & 3) * 16;
    half8 o0, o1;
    #pragma unroll
    for (int j = 0; j < 8; ++j) o0[j] = tile[t0 + j][d];
    #pragma unroll
    for (int j = 0; j < 8; ++j) o1[j] = tile[t0 + 8 + j][d];
    _Float16* dst = vt + ((size_t)h * 64 + d) * T_SEQ + tb * 64 + t0;
    *(half8*)(dst) = o0;
    *(half8*)(dst + 8) = o1;
}

// ---------------------------------------------------------------------------
// Flash attention, round 9: 4-wave blocks sharing K/V tiles via LDS.
// Block = (head, q-group of 4 chunks 4j..4j+3 = 128 q rows). ntiles = 2j+2;
// wave w owns chunk 4j+w (niter_w = 2j+1+(w>>1), within 1 tile of ntiles).
// Per tile: stage K[64][128B] + Vt[64][128B] ONCE via global_load_lds
// (full-line coalesced, pre-swizzled source — rule 21), double-buffered with
// issue-next-before-compute; 4 waves read swizzled ds_read_b128 fragments.
// This cuts L2 tile-reads 4x and replaces 32-line scattered 32B-useful
// fragment loads with coalesced staging — the round-7/8 per-iter wall.
// Compute body (swapped QK^T, in-register softmax, permlane pack, PV)
// unchanged from round 7.
// ---------------------------------------------------------------------------
__global__ __launch_bounds__(256)
void attn_tile_kernel(const _Float16* __restrict__ qg,
                      const _Float16* __restrict__ kg,
                      const _Float16* __restrict__ vtg,
                      _Float16* __restrict__ att) {
    __shared__ _Float16 Kl[2][4096];   // 2 x 8KB, swizzled [kv][d]
    __shared__ _Float16 Vl[2][4096];   // 2 x 8KB, swizzled [d][kv]

    const int tid  = threadIdx.x;
    const int lane = tid & 63;
    const int w    = tid >> 6;
    const int l31  = lane & 31;
    const int hi   = lane >> 5;

    // paired mapping: CUs hosting two blocks get ~constant total work
    const int b = blockIdx.x;          // 384
    const int h = b % NH;
    const int j = (b < 192) ? (31 - b / NH) : ((b - 192) / NH);

    const int cw      = 4 * j + w;          // this wave's q-chunk
    const int q       = cw * 32 + l31;      // this lane's q-row
    const int niter_w = 2 * j + 1 + (w >> 1);
    const int ntiles  = 2 * j + 2;

    const _Float16* Qh = qg  + ((size_t)h * T_SEQ + q) * DH;
    const _Float16* Kh = kg  + (size_t)h * T_SEQ * DH;
    const _Float16* Vh = vtg + (size_t)h * DH * T_SEQ;

    // Q fragments (B operand): col=lane&31=q, k(d) = 16*ks + hi*8 + jj
    half8 qf[4];
    #pragma unroll
    for (int ks = 0; ks < 4; ++ks)
        qf[ks] = *(const half8*)(Qh + ks * 16 + hi * 8);

    f32x16 o0v = {}, o1v = {};           // O^T d-tiles 0..31, 32..63
    float m = -1e30f, l = 0.f;

    // staging: 512 granules x 16B per tile, 2 per thread; source pre-swizzled
    const int g0 = tid, g1 = tid + 256;
    const int r0 = g0 >> 3, s0 = ((g0 & 7) ^ (r0 & 7)) * 8;
    const int r1 = g1 >> 3, s1 = ((g1 & 7) ^ (r1 & 7)) * 8;

    auto stage = [&](int p, int kvb) {
        async_copy16((char*)Kl[p] + g0 * 16, Kh + (size_t)(kvb + r0) * DH + s0);
        async_copy16((char*)Kl[p] + g1 * 16, Kh + (size_t)(kvb + r1) * DH + s1);
        async_copy16((char*)Vl[p] + g0 * 16, Vh + (size_t)r0 * T_SEQ + kvb + s0);
        async_copy16((char*)Vl[p] + g1 * 16, Vh + (size_t)r1 * T_SEQ + kvb + s1);
    };

    stage(0, 0);
    for (int it = 0; it < ntiles; ++it) {
        const int p = it & 1;
        __syncthreads();   // staged tile 'it' visible; prior buffer reads done
        if (it + 1 < ntiles) stage(p ^ 1, (it + 1) * 64);   // T3-lite prefetch
        if (it >= niter_w) continue;    // inactive wave still hits barrier

        const int kvb = it * 64;
        const char* Kb = (const char*)Kl[p];
        const char* Vb = (const char*)Vl[p];
        const int sw7 = l31 & 7;

        // ---- fragments from LDS (swizzled ds_read_b128)
        half8 kfA[4], kfB[4];
        #pragma unroll
        for (int ks = 0; ks < 4; ++ks) {
            const int gsl = (ks * 2 + hi) ^ sw7;
            kfA[ks] = *(const half8*)(Kb + l31 * 128 + (gsl << 4));
            kfB[ks] = *(const half8*)(Kb + (32 + l31) * 128 + (gsl << 4));
        }
        half8 vf[2][2][2];   // [kv-tile][dt][ks2]
        #pragma unroll
        for (int t = 0; t < 2; ++t)
            #pragma unroll
            for (int dt = 0; dt < 2; ++dt)
                #pragma unroll
                for (int ks2 = 0; ks2 < 2; ++ks2) {
                    const int gsl = (t * 4 + ks2 * 2 + hi) ^ sw7;
                    vf[t][dt][ks2] = *(const half8*)(Vb +
                        (dt * 32 + l31) * 128 + (gsl << 4));
                }

        // ---- S^T = K Q^T
        f32x16 sA = {}, sB = {};
        __builtin_amdgcn_s_setprio(1);
        #pragma unroll
        for (int ks = 0; ks < 4; ++ks) {
            sA = __builtin_amdgcn_mfma_f32_32x32x16_f16(kfA[ks], qf[ks], sA, 0, 0, 0);
            sB = __builtin_amdgcn_mfma_f32_32x32x16_f16(kfB[ks], qf[ks], sB, 0, 0, 0);
        }
        __builtin_amdgcn_s_setprio(0);

        // ---- causal mask (diagonal tile of this wave's chunk)
        if (it == niter_w - 1) {
            #pragma unroll
            for (int r = 0; r < 16; ++r) {
                const int off = (r & 3) + 8 * (r >> 2) + 4 * hi;
                if (kvb + off > q)      sA[r] = -1e30f;
                if (kvb + 32 + off > q) sB[r] = -1e30f;
            }
        }

        // ---- online softmax (exp2 domain): tree max, permlane cross-half
        float t8[8];
        #pragma unroll
        for (int r = 0; r < 8; ++r)
            t8[r] = fmaxf(fmaxf(sA[r], sA[r + 8]), fmaxf(sB[r], sB[r + 8]));
        float t4a = fmaxf(t8[0], t8[4]), t4b = fmaxf(t8[1], t8[5]);
        float t4c = fmaxf(t8[2], t8[6]), t4d = fmaxf(t8[3], t8[7]);
        float pmax = fmaxf(fmaxf(t4a, t4b), fmaxf(t4c, t4d));
        {
            auto r = __builtin_amdgcn_permlane32_swap(asu(pmax), asu(pmax), false, false);
            pmax = fmaxf(asf(r[0]), asf(r[1]));
        }

        if (!__all(pmax - m <= 11.0f)) {   // defer-max
            const float mnew = fmaxf(m, pmax);
            const float alpha = exp2f(m - mnew);
            m = mnew;
            l *= alpha;
            #pragma unroll
            for (int r = 0; r < 16; ++r) { o0v[r] *= alpha; o1v[r] *= alpha; }
        }
        #pragma unroll
        for (int r = 0; r < 16; ++r) sA[r] = exp2f(sA[r] - m);
        #pragma unroll
        for (int r = 0; r < 16; ++r) sB[r] = exp2f(sB[r] - m);
        float s8[8];
        #pragma unroll
        for (int r = 0; r < 8; ++r)
            s8[r] = (sA[r] + sA[r + 8]) + (sB[r] + sB[r + 8]);
        float rsum = ((s8[0] + s8[4]) + (s8[1] + s8[5])) +
                     ((s8[2] + s8[6]) + (s8[3] + s8[7]));
        {
            auto r = __builtin_amdgcn_permlane32_swap(asu(rsum), asu(rsum), false, false);
            rsum = asf(r[0]) + asf(r[1]);
        }
        l += rsum;

        // ---- pack P -> PV B-frags: 4 cvt_pkrtz + 2 permlane per group
        H8 pfA[2], pfB[2];
        #pragma unroll
        for (int ks2 = 0; ks2 < 2; ++ks2) {
            {
                const u32 a0 = pkrtz_u32(sA[8*ks2+0], sA[8*ks2+1]);
                const u32 a1 = pkrtz_u32(sA[8*ks2+2], sA[8*ks2+3]);
                const u32 b0 = pkrtz_u32(sA[8*ks2+4], sA[8*ks2+5]);
                const u32 b1 = pkrtz_u32(sA[8*ks2+6], sA[8*ks2+7]);
                auto r0 = __builtin_amdgcn_permlane32_swap(a0, b0, false, false);
                auto r1 = __builtin_amdgcn_permlane32_swap(a1, b1, false, false);
                pfA[ks2].u[0] = r0[0];
                pfA[ks2].u[1] = r1[0];
                pfA[ks2].u[2] = r0[1];
                pfA[ks2].u[3] = r1[1];
            }
            {
                const u32 a0 = pkrtz_u32(sB[8*ks2+0], sB[8*ks2+1]);
                const u32 a1 = pkrtz_u32(sB[8*ks2+2], sB[8*ks2+3]);
                const u32 b0 = pkrtz_u32(sB[8*ks2+4], sB[8*ks2+5]);
                const u32 b1 = pkrtz_u32(sB[8*ks2+6], sB[8*ks2+7]);
                auto r0 = __builtin_amdgcn_permlane32_swap(a0, b0, false, false);
                auto r1 = __builtin_amdgcn_permlane32_swap(a1, b1, false, false);
                pfB[ks2].u[0] = r0[0];
                pfB[ks2].u[1] = r1[0];
                pfB[ks2].u[2] = r0[1];
                pfB[ks2].u[3] = r1[1];
            }
        }

        // ---- PV: O^T[d][q] += V^T · P̂
        __builtin_amdgcn_s_setprio(1);
        #pragma unroll
        for (int ks2 = 0; ks2 < 2; ++ks2) {
            o0v = __builtin_amdgcn_mfma_f32_32x32x16_f16(vf[0][0][ks2], pfA[ks2].v, o0v, 0, 0, 0);
            o1v = __builtin_amdgcn_mfma_f32_32x32x16_f16(vf[0][1][ks2], pfA[ks2].v, o1v, 0, 0, 0);
            o0v = __builtin_amdgcn_mfma_f32_32x32x16_f16(vf[1][0][ks2], pfB[ks2].v, o0v, 0, 0, 0);
            o1v = __builtin_amdgcn_mfma_f32_32x32x16_f16(vf[1][1][ks2], pfB[ks2].v, o1v, 0, 0, 0);
        }
        __builtin_amdgcn_s_setprio(0);
    }

    // ---- epilogue: O^T[d][q] -> att[q][h*64+d], normalize by l
    const float inv = 1.0f / l;
    _Float16* ap = att + (size_t)q * DM + h * DH + 4 * hi;
    #pragma unroll
    for (int g = 0; g < 4; ++g) {
        half4v w0 = { (_Float16)(o0v[4*g+0] * inv), (_Float16)(o0v[4*g+1] * inv),
                      (_Float16)(o0v[4*g+2] * inv), (_Float16)(o0v[4*g+3] * inv) };
        half4v w1 = { (_Float16)(o1v[4*g+0] * inv), (_Float16)(o1v[4*g+1] * inv),
                      (_Float16)(o1v[4*g+2] * inv), (_Float16)(o1v[4*g+3] * inv) };
        *(half4v*)(ap + 8 * g)      = w0;
        *(half4v*)(ap + 32 + 8 * g) = w1;
    }
}

// ---------------------------------------------------------------------------
extern "C" void kernel_launch(void* const* d_in, const int* in_sizes, int n_in,
                              void* d_out, int out_size, void* d_ws, size_t ws_size,
                              hipStream_t stream) {
    const float* x      = (const float*)d_in[0];
    const float* w_qkv  = (const float*)d_in[1];
    const float* w_proj = (const float*)d_in[2];
    const float* b_proj = (const float*)d_in[3];
    float* out = (float*)d_out;

    _Float16* wsb = (_Float16*)d_ws;
    const size_t XS = (size_t)T_SEQ * DM;
    const size_t HS = (size_t)NH * T_SEQ * DH;
    _Float16* xh     = wsb;
    _Float16* wqkvT  = xh + XS;
    _Float16* wprojT = wqkvT + (size_t)NC * DM;
    _Float16* q      = wprojT + (size_t)DM * DM;
    _Float16* k      = q + HS;
    _Float16* v      = k + HS;
    _Float16* vt     = v + HS;
    _Float16* att    = vt + HS;

    convert_x_kernel<<<dim3(1536), 256, 0, stream>>>(x, xh);
    transpose_convert_kernel<<<dim3(36, 12), 256, 0, stream>>>(w_qkv, wqkvT, DM, NC);
    transpose_convert_kernel<<<dim3(12, 12), 256, 0, stream>>>(w_proj, wprojT, DM, DM);
    qkv_mfma_kernel<<<dim3(576), 256, 0, stream>>>(xh, wqkvT, q, k, v);
    vt_kernel<<<dim3(64, NH), 256, 0, stream>>>(v, vt);
    attn_tile_kernel<<<dim3(384), 256, 0, stream>>>(q, k, vt, att);
    proj_mfma_kernel<<<dim3(192), 256, 0, stream>>>(att, wprojT, b_proj, out);
}

// Round 10
// 175.957 us; speedup vs baseline: 1.2416x; 1.0002x over previous
//
#include <hip/hip_runtime.h>

#define T_SEQ 4096
#define DM    768
#define NH    12
#define DH    64
#define NC    2304   // 3 * DM

using half8  = __attribute__((ext_vector_type(8))) _Float16;
using half4v = __attribute__((ext_vector_type(4))) _Float16;
using f32x4  = __attribute__((ext_vector_type(4))) float;
using f32x16 = __attribute__((ext_vector_type(16))) float;
typedef unsigned int u32;

union H8 { half8 v; u32 u[4]; };

// cvt_pkrtz returns __fp16 ext_vector(2); bit-cast straight to u32.
__device__ __forceinline__ u32 pkrtz_u32(float a, float b) {
    return __builtin_bit_cast(u32, __builtin_amdgcn_cvt_pkrtz(a, b));
}
__device__ __forceinline__ float asf(u32 x) { return __builtin_bit_cast(float, x); }
__device__ __forceinline__ u32 asu(float x) { return __builtin_bit_cast(u32, x); }

__device__ __forceinline__ void async_copy16(void* lds, const void* g) {
    __builtin_amdgcn_global_load_lds(
        (const __attribute__((address_space(1))) u32*)g,
        (__attribute__((address_space(3))) u32*)lds, 16, 0, 0);
}

// ---------------------------------------------------------------------------
// x (fp32) -> xh (fp16)
// ---------------------------------------------------------------------------
__global__ __launch_bounds__(256)
void convert_x_kernel(const float* __restrict__ x, _Float16* __restrict__ xh) {
    const size_t i = ((size_t)blockIdx.x * 256 + threadIdx.x) * 8;
    float4 a = *(const float4*)(x + i);
    float4 b = *(const float4*)(x + i + 4);
    half8 o = { (_Float16)a.x, (_Float16)a.y, (_Float16)a.z, (_Float16)a.w,
                (_Float16)b.x, (_Float16)b.y, (_Float16)b.z, (_Float16)b.w };
    *(half8*)(xh + i) = o;
}

// ---------------------------------------------------------------------------
// src [R][C] fp32 -> dst [C][R] fp16 (weight transpose+convert)
// ---------------------------------------------------------------------------
__global__ __launch_bounds__(256)
void transpose_convert_kernel(const float* __restrict__ src,
                              _Float16* __restrict__ dst, int R, int C) {
    __shared__ _Float16 tile[64][72];
    const int tid = threadIdx.x;
    const int tc0 = blockIdx.x * 64;
    const int tr0 = blockIdx.y * 64;
    const int r = tid >> 2, c4 = (tid & 3) * 16;
    const float* sp = src + (size_t)(tr0 + r) * C + tc0 + c4;
    #pragma unroll
    for (int j = 0; j < 16; j += 4) {
        float4 t4 = *(const float4*)(sp + j);
        tile[r][c4 + j + 0] = (_Float16)t4.x;
        tile[r][c4 + j + 1] = (_Float16)t4.y;
        tile[r][c4 + j + 2] = (_Float16)t4.z;
        tile[r][c4 + j + 3] = (_Float16)t4.w;
    }
    __syncthreads();
    const int c = tid >> 2, r4 = (tid & 3) * 16;
    half8 o0, o1;
    #pragma unroll
    for (int j = 0; j < 8; ++j) o0[j] = tile[r4 + j][c];
    #pragma unroll
    for (int j = 0; j < 8; ++j) o1[j] = tile[r4 + 8 + j][c];
    _Float16* dp = dst + (size_t)(tc0 + c) * R + tr0 + r4;
    *(half8*)(dp) = o0;
    *(half8*)(dp + 8) = o1;
}

// ---------------------------------------------------------------------------
// fp16 MFMA GEMM (m97 structure)
// ---------------------------------------------------------------------------
__global__ __launch_bounds__(256, 2)
void qkv_mfma_kernel(const _Float16* __restrict__ A,
                     const _Float16* __restrict__ Bt,
                     _Float16* __restrict__ q, _Float16* __restrict__ k,
                     _Float16* __restrict__ v) {
    __shared__ _Float16 Alds[128 * 64];
    __shared__ _Float16 Blds[128 * 64];
    const int tid  = threadIdx.x;
    const int lane = tid & 63;
    const int w    = tid >> 6;
    const int wr = w >> 1, wc = w & 1;
    const int lrow = lane >> 4, lcol = lane & 15;

    const int bid  = blockIdx.x;                    // 576 = 8 * 72
    const int virt = (bid & 7) * 72 + (bid >> 3);
    const int cbn  = virt % 18, rbn = virt / 18;

    const _Float16* Ag = A  + (size_t)rbn * 128 * DM;
    const _Float16* Bg = Bt + (size_t)cbn * 128 * DM;

    int srow[4], scol[4];
    #pragma unroll
    for (int i = 0; i < 4; ++i) {
        const int idx = i * 256 + tid;
        srow[i] = idx >> 3;
        scol[i] = ((idx & 7) ^ (srow[i] & 7)) * 8;
    }

    f32x4 acc[4][4];
    #pragma unroll
    for (int mf = 0; mf < 4; ++mf)
        #pragma unroll
        for (int nf = 0; nf < 4; ++nf) acc[mf][nf] = (f32x4){0.f, 0.f, 0.f, 0.f};

    for (int kt = 0; kt < DM / 64; ++kt) {
        const int k0 = kt * 64;
        __syncthreads();
        #pragma unroll
        for (int i = 0; i < 4; ++i) {
            async_copy16((char*)Alds + (i * 256 + w * 64) * 16,
                         Ag + (size_t)srow[i] * DM + k0 + scol[i]);
            async_copy16((char*)Blds + (i * 256 + w * 64) * 16,
                         Bg + (size_t)srow[i] * DM + k0 + scol[i]);
        }
        __syncthreads();
        #pragma unroll
        for (int kh = 0; kh < 2; ++kh) {
            half8 af[4], bf[4];
            const int ag = kh * 4 + lrow;
            #pragma unroll
            for (int f = 0; f < 4; ++f) {
                const int ar = wr * 64 + f * 16 + lcol;
                af[f] = *(const half8*)((const char*)Alds +
                          ar * 128 + ((ag ^ (ar & 7)) << 4));
                const int br = wc * 64 + f * 16 + lcol;
                bf[f] = *(const half8*)((const char*)Blds +
                          br * 128 + ((ag ^ (br & 7)) << 4));
            }
            #pragma unroll
            for (int mf = 0; mf < 4; ++mf)
                #pragma unroll
                for (int nf = 0; nf < 4; ++nf)
                    acc[mf][nf] = __builtin_amdgcn_mfma_f32_16x16x32_f16(
                        af[mf], bf[nf], acc[mf][nf], 0, 0, 0);
        }
    }

    #pragma unroll
    for (int nf = 0; nf < 4; ++nf) {
        const int n = cbn * 128 + wc * 64 + nf * 16 + lcol;
        const int head  = n / 192;
        const int which = (n >> 6) % 3;
        const int d = n & 63;
        _Float16* dst = (which == 0) ? q : (which == 1) ? k : v;
        const float sc = (which == 0) ? 0.18033688011112042f : 1.0f;
        dst += (size_t)head * T_SEQ * DH + d;
        #pragma unroll
        for (int mf = 0; mf < 4; ++mf) {
            const int t0 = rbn * 128 + wr * 64 + mf * 16 + lrow * 4;
            #pragma unroll
            for (int r = 0; r < 4; ++r)
                dst[(size_t)(t0 + r) * DH] = (_Float16)(acc[mf][nf][r] * sc);
        }
    }
}

__global__ __launch_bounds__(256, 2)
void proj_mfma_kernel(const _Float16* __restrict__ A,
                      const _Float16* __restrict__ Bt,
                      const float* __restrict__ bias, float* __restrict__ out) {
    __shared__ _Float16 Alds[128 * 64];
    __shared__ _Float16 Blds[128 * 64];
    const int tid  = threadIdx.x;
    const int lane = tid & 63;
    const int w    = tid >> 6;
    const int wr = w >> 1, wc = w & 1;
    const int lrow = lane >> 4, lcol = lane & 15;

    const int bid  = blockIdx.x;                    // 192 = 8 * 24
    const int virt = (bid & 7) * 24 + (bid >> 3);
    const int cbn  = virt % 6, rbn = virt / 6;

    const _Float16* Ag = A  + (size_t)rbn * 128 * DM;
    const _Float16* Bg = Bt + (size_t)cbn * 128 * DM;

    int srow[4], scol[4];
    #pragma unroll
    for (int i = 0; i < 4; ++i) {
        const int idx = i * 256 + tid;
        srow[i] = idx >> 3;
        scol[i] = ((idx & 7) ^ (srow[i] & 7)) * 8;
    }

    f32x4 acc[4][4];
    #pragma unroll
    for (int mf = 0; mf < 4; ++mf)
        #pragma unroll
        for (int nf = 0; nf < 4; ++nf) acc[mf][nf] = (f32x4){0.f, 0.f, 0.f, 0.f};

    for (int kt = 0; kt < DM / 64; ++kt) {
        const int k0 = kt * 64;
        __syncthreads();
        #pragma unroll
        for (int i = 0; i < 4; ++i) {
            async_copy16((char*)Alds + (i * 256 + w * 64) * 16,
                         Ag + (size_t)srow[i] * DM + k0 + scol[i]);
            async_copy16((char*)Blds + (i * 256 + w * 64) * 16,
                         Bg + (size_t)srow[i] * DM + k0 + scol[i]);
        }
        __syncthreads();
        #pragma unroll
        for (int kh = 0; kh < 2; ++kh) {
            half8 af[4], bf[4];
            const int ag = kh * 4 + lrow;
            #pragma unroll
            for (int f = 0; f < 4; ++f) {
                const int ar = wr * 64 + f * 16 + lcol;
                af[f] = *(const half8*)((const char*)Alds +
                          ar * 128 + ((ag ^ (ar & 7)) << 4));
                const int br = wc * 64 + f * 16 + lcol;
                bf[f] = *(const half8*)((const char*)Blds +
                          br * 128 + ((ag ^ (br & 7)) << 4));
            }
            #pragma unroll
            for (int mf = 0; mf < 4; ++mf)
                #pragma unroll
                for (int nf = 0; nf < 4; ++nf)
                    acc[mf][nf] = __builtin_amdgcn_mfma_f32_16x16x32_f16(
                        af[mf], bf[nf], acc[mf][nf], 0, 0, 0);
        }
    }

    #pragma unroll
    for (int nf = 0; nf < 4; ++nf) {
        const int n = cbn * 128 + wc * 64 + nf * 16 + lcol;
        const float b = bias[n];
        #pragma unroll
        for (int mf = 0; mf < 4; ++mf) {
            const int t0 = rbn * 128 + wr * 64 + mf * 16 + lrow * 4;
            #pragma unroll
            for (int r = 0; r < 4; ++r)
                out[(size_t)(t0 + r) * DM + n] = acc[mf][nf][r] + b;
        }
    }
}

// ---------------------------------------------------------------------------
// V [h][t][d] -> Vt [h][d][t] (fp16)
// ---------------------------------------------------------------------------
__global__ __launch_bounds__(256)
void vt_kernel(const _Float16* __restrict__ v, _Float16* __restrict__ vt) {
    __shared__ _Float16 tile[64][65];
    const int tid = threadIdx.x;
    const int tb = blockIdx.x, h = blockIdx.y;
    const int r = tid >> 2, c0 = (tid & 3) * 16;
    const _Float16* src = v + ((size_t)h * T_SEQ + tb * 64 + r) * 64 + c0;
    half8 a0 = *(const half8*)(src);
    half8 a1 = *(const half8*)(src + 8);
    #pragma unroll
    for (int j = 0; j < 8; ++j) tile[r][c0 + j] = a0[j];
    #pragma unroll
    for (int j = 0; j < 8; ++j) tile[r][c0 + 8 + j] = a1[j];
    __syncthreads();
    const int d = tid >> 2, t0 = (tid & 3) * 16;
    half8 o0, o1;
    #pragma unroll
    for (int j = 0; j < 8; ++j) o0[j] = tile[t0 + j][d];
    #pragma unroll
    for (int j = 0; j < 8; ++j) o1[j] = tile[t0 + 8 + j][d];
    _Float16* dst = vt + ((size_t)h * 64 + d) * T_SEQ + tb * 64 + t0;
    *(half8*)(dst) = o0;
    *(half8*)(dst + 8) = o1;
}

// ---------------------------------------------------------------------------
// Flash attention, round 9: 4-wave blocks sharing K/V tiles via LDS.
// Block = (head, q-group of 4 chunks 4j..4j+3 = 128 q rows). ntiles = 2j+2;
// wave w owns chunk 4j+w (niter_w = 2j+1+(w>>1), within 1 tile of ntiles).
// Per tile: stage K[64][128B] + Vt[64][128B] ONCE via global_load_lds
// (full-line coalesced, pre-swizzled source — rule 21), double-buffered with
// issue-next-before-compute; 4 waves read swizzled ds_read_b128 fragments.
// This cuts L2 tile-reads 4x and replaces 32-line scattered 32B-useful
// fragment loads with coalesced staging — the round-7/8 per-iter wall.
// Compute body (swapped QK^T, in-register softmax, permlane pack, PV)
// unchanged from round 7.
// ---------------------------------------------------------------------------
__global__ __launch_bounds__(256)
void attn_tile_kernel(const _Float16* __restrict__ qg,
                      const _Float16* __restrict__ kg,
                      const _Float16* __restrict__ vtg,
                      _Float16* __restrict__ att) {
    __shared__ _Float16 Kl[2][4096];   // 2 x 8KB, swizzled [kv][d]
    __shared__ _Float16 Vl[2][4096];   // 2 x 8KB, swizzled [d][kv]

    const int tid  = threadIdx.x;
    const int lane = tid & 63;
    const int w    = tid >> 6;
    const int l31  = lane & 31;
    const int hi   = lane >> 5;

    // paired mapping: CUs hosting two blocks get ~constant total work
    const int b = blockIdx.x;          // 384
    const int h = b % NH;
    const int j = (b < 192) ? (31 - b / NH) : ((b - 192) / NH);

    const int cw      = 4 * j + w;          // this wave's q-chunk
    const int q       = cw * 32 + l31;      // this lane's q-row
    const int niter_w = 2 * j + 1 + (w >> 1);
    const int ntiles  = 2 * j + 2;

    const _Float16* Qh = qg  + ((size_t)h * T_SEQ + q) * DH;
    const _Float16* Kh = kg  + (size_t)h * T_SEQ * DH;
    const _Float16* Vh = vtg + (size_t)h * DH * T_SEQ;

    // Q fragments (B operand): col=lane&31=q, k(d) = 16*ks + hi*8 + jj
    half8 qf[4];
    #pragma unroll
    for (int ks = 0; ks < 4; ++ks)
        qf[ks] = *(const half8*)(Qh + ks * 16 + hi * 8);

    f32x16 o0v = {}, o1v = {};           // O^T d-tiles 0..31, 32..63
    float m = -1e30f, l = 0.f;

    // staging: 512 granules x 16B per tile, 2 per thread; source pre-swizzled
    const int g0 = tid, g1 = tid + 256;
    const int r0 = g0 >> 3, s0 = ((g0 & 7) ^ (r0 & 7)) * 8;
    const int r1 = g1 >> 3, s1 = ((g1 & 7) ^ (r1 & 7)) * 8;

    auto stage = [&](int p, int kvb) {
        async_copy16((char*)Kl[p] + g0 * 16, Kh + (size_t)(kvb + r0) * DH + s0);
        async_copy16((char*)Kl[p] + g1 * 16, Kh + (size_t)(kvb + r1) * DH + s1);
        async_copy16((char*)Vl[p] + g0 * 16, Vh + (size_t)r0 * T_SEQ + kvb + s0);
        async_copy16((char*)Vl[p] + g1 * 16, Vh + (size_t)r1 * T_SEQ + kvb + s1);
    };

    stage(0, 0);
    for (int it = 0; it < ntiles; ++it) {
        const int p = it & 1;
        __syncthreads();   // staged tile 'it' visible; prior buffer reads done
        if (it + 1 < ntiles) stage(p ^ 1, (it + 1) * 64);   // T3-lite prefetch
        if (it >= niter_w) continue;    // inactive wave still hits barrier

        const int kvb = it * 64;
        const char* Kb = (const char*)Kl[p];
        const char* Vb = (const char*)Vl[p];
        const int sw7 = l31 & 7;

        // ---- fragments from LDS (swizzled ds_read_b128)
        half8 kfA[4], kfB[4];
        #pragma unroll
        for (int ks = 0; ks < 4; ++ks) {
            const int gsl = (ks * 2 + hi) ^ sw7;
            kfA[ks] = *(const half8*)(Kb + l31 * 128 + (gsl << 4));
            kfB[ks] = *(const half8*)(Kb + (32 + l31) * 128 + (gsl << 4));
        }
        half8 vf[2][2][2];   // [kv-tile][dt][ks2]
        #pragma unroll
        for (int t = 0; t < 2; ++t)
            #pragma unroll
            for (int dt = 0; dt < 2; ++dt)
                #pragma unroll
                for (int ks2 = 0; ks2 < 2; ++ks2) {
                    const int gsl = (t * 4 + ks2 * 2 + hi) ^ sw7;
                    vf[t][dt][ks2] = *(const half8*)(Vb +
                        (dt * 32 + l31) * 128 + (gsl << 4));
                }

        // ---- S^T = K Q^T
        f32x16 sA = {}, sB = {};
        __builtin_amdgcn_s_setprio(1);
        #pragma unroll
        for (int ks = 0; ks < 4; ++ks) {
            sA = __builtin_amdgcn_mfma_f32_32x32x16_f16(kfA[ks], qf[ks], sA, 0, 0, 0);
            sB = __builtin_amdgcn_mfma_f32_32x32x16_f16(kfB[ks], qf[ks], sB, 0, 0, 0);
        }
        __builtin_amdgcn_s_setprio(0);

        // ---- causal mask (diagonal tile of this wave's chunk)
        if (it == niter_w - 1) {
            #pragma unroll
            for (int r = 0; r < 16; ++r) {
                const int off = (r & 3) + 8 * (r >> 2) + 4 * hi;
                if (kvb + off > q)      sA[r] = -1e30f;
                if (kvb + 32 + off > q) sB[r] = -1e30f;
            }
        }

        // ---- online softmax (exp2 domain): tree max, permlane cross-half
        float t8[8];
        #pragma unroll
        for (int r = 0; r < 8; ++r)
            t8[r] = fmaxf(fmaxf(sA[r], sA[r + 8]), fmaxf(sB[r], sB[r + 8]));
        float t4a = fmaxf(t8[0], t8[4]), t4b = fmaxf(t8[1], t8[5]);
        float t4c = fmaxf(t8[2], t8[6]), t4d = fmaxf(t8[3], t8[7]);
        float pmax = fmaxf(fmaxf(t4a, t4b), fmaxf(t4c, t4d));
        {
            auto r = __builtin_amdgcn_permlane32_swap(asu(pmax), asu(pmax), false, false);
            pmax = fmaxf(asf(r[0]), asf(r[1]));
        }

        if (!__all(pmax - m <= 11.0f)) {   // defer-max
            const float mnew = fmaxf(m, pmax);
            const float alpha = exp2f(m - mnew);
            m = mnew;
            l *= alpha;
            #pragma unroll
            for (int r = 0; r < 16; ++r) { o0v[r] *= alpha; o1v[r] *= alpha; }
        }
        #pragma unroll
        for (int r = 0; r < 16; ++r) sA[r] = exp2f(sA[r] - m);
        #pragma unroll
        for (int r = 0; r < 16; ++r) sB[r] = exp2f(sB[r] - m);
        float s8[8];
        #pragma unroll
        for (int r = 0; r < 8; ++r)
            s8[r] = (sA[r] + sA[r + 8]) + (sB[r] + sB[r + 8]);
        float rsum = ((s8[0] + s8[4]) + (s8[1] + s8[5])) +
                     ((s8[2] + s8[6]) + (s8[3] + s8[7]));
        {
            auto r = __builtin_amdgcn_permlane32_swap(asu(rsum), asu(rsum), false, false);
            rsum = asf(r[0]) + asf(r[1]);
        }
        l += rsum;

        // ---- pack P -> PV B-frags: 4 cvt_pkrtz + 2 permlane per group
        H8 pfA[2], pfB[2];
        #pragma unroll
        for (int ks2 = 0; ks2 < 2; ++ks2) {
            {
                const u32 a0 = pkrtz_u32(sA[8*ks2+0], sA[8*ks2+1]);
                const u32 a1 = pkrtz_u32(sA[8*ks2+2], sA[8*ks2+3]);
                const u32 b0 = pkrtz_u32(sA[8*ks2+4], sA[8*ks2+5]);
                const u32 b1 = pkrtz_u32(sA[8*ks2+6], sA[8*ks2+7]);
                auto r0 = __builtin_amdgcn_permlane32_swap(a0, b0, false, false);
                auto r1 = __builtin_amdgcn_permlane32_swap(a1, b1, false, false);
                pfA[ks2].u[0] = r0[0];
                pfA[ks2].u[1] = r1[0];
                pfA[ks2].u[2] = r0[1];
                pfA[ks2].u[3] = r1[1];
            }
            {
                const u32 a0 = pkrtz_u32(sB[8*ks2+0], sB[8*ks2+1]);
                const u32 a1 = pkrtz_u32(sB[8*ks2+2], sB[8*ks2+3]);
                const u32 b0 = pkrtz_u32(sB[8*ks2+4], sB[8*ks2+5]);
                const u32 b1 = pkrtz_u32(sB[8*ks2+6], sB[8*ks2+7]);
                auto r0 = __builtin_amdgcn_permlane32_swap(a0, b0, false, false);
                auto r1 = __builtin_amdgcn_permlane32_swap(a1, b1, false, false);
                pfB[ks2].u[0] = r0[0];
                pfB[ks2].u[1] = r1[0];
                pfB[ks2].u[2] = r0[1];
                pfB[ks2].u[3] = r1[1];
            }
        }

        // ---- PV: O^T[d][q] += V^T · P̂
        __builtin_amdgcn_s_setprio(1);
        #pragma unroll
        for (int ks2 = 0; ks2 < 2; ++ks2) {
            o0v = __builtin_amdgcn_mfma_f32_32x32x16_f16(vf[0][0][ks2], pfA[ks2].v, o0v, 0, 0, 0);
            o1v = __builtin_amdgcn_mfma_f32_32x32x16_f16(vf[0][1][ks2], pfA[ks2].v, o1v, 0, 0, 0);
            o0v = __builtin_amdgcn_mfma_f32_32x32x16_f16(vf[1][0][ks2], pfB[ks2].v, o0v, 0, 0, 0);
            o1v = __builtin_amdgcn_mfma_f32_32x32x16_f16(vf[1][1][ks2], pfB[ks2].v, o1v, 0, 0, 0);
        }
        __builtin_amdgcn_s_setprio(0);
    }

    // ---- epilogue: O^T[d][q] -> att[q][h*64+d], normalize by l
    const float inv = 1.0f / l;
    _Float16* ap = att + (size_t)q * DM + h * DH + 4 * hi;
    #pragma unroll
    for (int g = 0; g < 4; ++g) {
        half4v w0 = { (_Float16)(o0v[4*g+0] * inv), (_Float16)(o0v[4*g+1] * inv),
                      (_Float16)(o0v[4*g+2] * inv), (_Float16)(o0v[4*g+3] * inv) };
        half4v w1 = { (_Float16)(o1v[4*g+0] * inv), (_Float16)(o1v[4*g+1] * inv),
                      (_Float16)(o1v[4*g+2] * inv), (_Float16)(o1v[4*g+3] * inv) };
        *(half4v*)(ap + 8 * g)      = w0;
        *(half4v*)(ap + 32 + 8 * g) = w1;
    }
}

// ---------------------------------------------------------------------------
extern "C" void kernel_launch(void* const* d_in, const int* in_sizes, int n_in,
                              void* d_out, int out_size, void* d_ws, size_t ws_size,
                              hipStream_t stream) {
    const float* x      = (const float*)d_in[0];
    const float* w_qkv  = (const float*)d_in[1];
    const float* w_proj = (const float*)d_in[2];
    const float* b_proj = (const float*)d_in[3];
    float* out = (float*)d_out;

    _Float16* wsb = (_Float16*)d_ws;
    const size_t XS = (size_t)T_SEQ * DM;
    const size_t HS = (size_t)NH * T_SEQ * DH;
    _Float16* xh     = wsb;
    _Float16* wqkvT  = xh + XS;
    _Float16* wprojT = wqkvT + (size_t)NC * DM;
    _Float16* q      = wprojT + (size_t)DM * DM;
    _Float16* k      = q + HS;
    _Float16* v      = k + HS;
    _Float16* vt     = v + HS;
    _Float16* att    = vt + HS;

    convert_x_kernel<<<dim3(1536), 256, 0, stream>>>(x, xh);
    transpose_convert_kernel<<<dim3(36, 12), 256, 0, stream>>>(w_qkv, wqkvT, DM, NC);
    transpose_convert_kernel<<<dim3(12, 12), 256, 0, stream>>>(w_proj, wprojT, DM, DM);
    qkv_mfma_kernel<<<dim3(576), 256, 0, stream>>>(xh, wqkvT, q, k, v);
    vt_kernel<<<dim3(64, NH), 256, 0, stream>>>(v, vt);
    attn_tile_kernel<<<dim3(384), 256, 0, stream>>>(q, k, vt, att);
    proj_mfma_kernel<<<dim3(192), 256, 0, stream>>>(att, wprojT, b_proj, out);
}

// Round 11
// 138.132 us; speedup vs baseline: 1.5816x; 1.2738x over previous
//
#include <hip/hip_runtime.h>

#define T_SEQ 4096
#define DM    768
#define NH    12
#define DH    64
#define NC    2304   // 3 * DM

using half8  = __attribute__((ext_vector_type(8))) _Float16;
using half4v = __attribute__((ext_vector_type(4))) _Float16;
using f32x4  = __attribute__((ext_vector_type(4))) float;
using f32x16 = __attribute__((ext_vector_type(16))) float;
typedef unsigned int u32;

union H8 { half8 v; u32 u[4]; };

// cvt_pkrtz returns __fp16 ext_vector(2); bit-cast straight to u32.
__device__ __forceinline__ u32 pkrtz_u32(float a, float b) {
    return __builtin_bit_cast(u32, __builtin_amdgcn_cvt_pkrtz(a, b));
}
__device__ __forceinline__ float asf(u32 x) { return __builtin_bit_cast(float, x); }
__device__ __forceinline__ u32 asu(float x) { return __builtin_bit_cast(u32, x); }

__device__ __forceinline__ void async_copy16(void* lds, const void* g) {
    __builtin_amdgcn_global_load_lds(
        (const __attribute__((address_space(1))) u32*)g,
        (__attribute__((address_space(3))) u32*)lds, 16, 0, 0);
}

// ---------------------------------------------------------------------------
// x (fp32) -> xh (fp16)
// ---------------------------------------------------------------------------
__global__ __launch_bounds__(256)
void convert_x_kernel(const float* __restrict__ x, _Float16* __restrict__ xh) {
    const size_t i = ((size_t)blockIdx.x * 256 + threadIdx.x) * 8;
    float4 a = *(const float4*)(x + i);
    float4 b = *(const float4*)(x + i + 4);
    half8 o = { (_Float16)a.x, (_Float16)a.y, (_Float16)a.z, (_Float16)a.w,
                (_Float16)b.x, (_Float16)b.y, (_Float16)b.z, (_Float16)b.w };
    *(half8*)(xh + i) = o;
}

// ---------------------------------------------------------------------------
// src [R][C] fp32 -> dst [C][R] fp16 (weight transpose+convert)
// ---------------------------------------------------------------------------
__global__ __launch_bounds__(256)
void transpose_convert_kernel(const float* __restrict__ src,
                              _Float16* __restrict__ dst, int R, int C) {
    __shared__ _Float16 tile[64][72];
    const int tid = threadIdx.x;
    const int tc0 = blockIdx.x * 64;
    const int tr0 = blockIdx.y * 64;
    const int r = tid >> 2, c4 = (tid & 3) * 16;
    const float* sp = src + (size_t)(tr0 + r) * C + tc0 + c4;
    #pragma unroll
    for (int j = 0; j < 16; j += 4) {
        float4 t4 = *(const float4*)(sp + j);
        tile[r][c4 + j + 0] = (_Float16)t4.x;
        tile[r][c4 + j + 1] = (_Float16)t4.y;
        tile[r][c4 + j + 2] = (_Float16)t4.z;
        tile[r][c4 + j + 3] = (_Float16)t4.w;
    }
    __syncthreads();
    const int c = tid >> 2, r4 = (tid & 3) * 16;
    half8 o0, o1;
    #pragma unroll
    for (int j = 0; j < 8; ++j) o0[j] = tile[r4 + j][c];
    #pragma unroll
    for (int j = 0; j < 8; ++j) o1[j] = tile[r4 + 8 + j][c];
    _Float16* dp = dst + (size_t)(tc0 + c) * R + tr0 + r4;
    *(half8*)(dp) = o0;
    *(half8*)(dp + 8) = o1;
}

// ---------------------------------------------------------------------------
// fp16 MFMA GEMM (m97 structure)
// ---------------------------------------------------------------------------
__global__ __launch_bounds__(256, 2)
void qkv_mfma_kernel(const _Float16* __restrict__ A,
                     const _Float16* __restrict__ Bt,
                     _Float16* __restrict__ q, _Float16* __restrict__ k,
                     _Float16* __restrict__ v) {
    __shared__ _Float16 Alds[128 * 64];
    __shared__ _Float16 Blds[128 * 64];
    const int tid  = threadIdx.x;
    const int lane = tid & 63;
    const int w    = tid >> 6;
    const int wr = w >> 1, wc = w & 1;
    const int lrow = lane >> 4, lcol = lane & 15;

    const int bid  = blockIdx.x;                    // 576 = 8 * 72
    const int virt = (bid & 7) * 72 + (bid >> 3);
    const int cbn  = virt % 18, rbn = virt / 18;

    const _Float16* Ag = A  + (size_t)rbn * 128 * DM;
    const _Float16* Bg = Bt + (size_t)cbn * 128 * DM;

    int srow[4], scol[4];
    #pragma unroll
    for (int i = 0; i < 4; ++i) {
        const int idx = i * 256 + tid;
        srow[i] = idx >> 3;
        scol[i] = ((idx & 7) ^ (srow[i] & 7)) * 8;
    }

    f32x4 acc[4][4];
    #pragma unroll
    for (int mf = 0; mf < 4; ++mf)
        #pragma unroll
        for (int nf = 0; nf < 4; ++nf) acc[mf][nf] = (f32x4){0.f, 0.f, 0.f, 0.f};

    for (int kt = 0; kt < DM / 64; ++kt) {
        const int k0 = kt * 64;
        __syncthreads();
        #pragma unroll
        for (int i = 0; i < 4; ++i) {
            async_copy16((char*)Alds + (i * 256 + w * 64) * 16,
                         Ag + (size_t)srow[i] * DM + k0 + scol[i]);
            async_copy16((char*)Blds + (i * 256 + w * 64) * 16,
                         Bg + (size_t)srow[i] * DM + k0 + scol[i]);
        }
        __syncthreads();
        #pragma unroll
        for (int kh = 0; kh < 2; ++kh) {
            half8 af[4], bf[4];
            const int ag = kh * 4 + lrow;
            #pragma unroll
            for (int f = 0; f < 4; ++f) {
                const int ar = wr * 64 + f * 16 + lcol;
                af[f] = *(const half8*)((const char*)Alds +
                          ar * 128 + ((ag ^ (ar & 7)) << 4));
                const int br = wc * 64 + f * 16 + lcol;
                bf[f] = *(const half8*)((const char*)Blds +
                          br * 128 + ((ag ^ (br & 7)) << 4));
            }
            #pragma unroll
            for (int mf = 0; mf < 4; ++mf)
                #pragma unroll
                for (int nf = 0; nf < 4; ++nf)
                    acc[mf][nf] = __builtin_amdgcn_mfma_f32_16x16x32_f16(
                        af[mf], bf[nf], acc[mf][nf], 0, 0, 0);
        }
    }

    #pragma unroll
    for (int nf = 0; nf < 4; ++nf) {
        const int n = cbn * 128 + wc * 64 + nf * 16 + lcol;
        const int head  = n / 192;
        const int which = (n >> 6) % 3;
        const int d = n & 63;
        _Float16* dst = (which == 0) ? q : (which == 1) ? k : v;
        const float sc = (which == 0) ? 0.18033688011112042f : 1.0f;
        dst += (size_t)head * T_SEQ * DH + d;
        #pragma unroll
        for (int mf = 0; mf < 4; ++mf) {
            const int t0 = rbn * 128 + wr * 64 + mf * 16 + lrow * 4;
            #pragma unroll
            for (int r = 0; r < 4; ++r)
                dst[(size_t)(t0 + r) * DH] = (_Float16)(acc[mf][nf][r] * sc);
        }
    }
}

__global__ __launch_bounds__(256, 2)
void proj_mfma_kernel(const _Float16* __restrict__ A,
                      const _Float16* __restrict__ Bt,
                      const float* __restrict__ bias, float* __restrict__ out) {
    __shared__ _Float16 Alds[128 * 64];
    __shared__ _Float16 Blds[128 * 64];
    const int tid  = threadIdx.x;
    const int lane = tid & 63;
    const int w    = tid >> 6;
    const int wr = w >> 1, wc = w & 1;
    const int lrow = lane >> 4, lcol = lane & 15;

    const int bid  = blockIdx.x;                    // 192 = 8 * 24
    const int virt = (bid & 7) * 24 + (bid >> 3);
    const int cbn  = virt % 6, rbn = virt / 6;

    const _Float16* Ag = A  + (size_t)rbn * 128 * DM;
    const _Float16* Bg = Bt + (size_t)cbn * 128 * DM;

    int srow[4], scol[4];
    #pragma unroll
    for (int i = 0; i < 4; ++i) {
        const int idx = i * 256 + tid;
        srow[i] = idx >> 3;
        scol[i] = ((idx & 7) ^ (srow[i] & 7)) * 8;
    }

    f32x4 acc[4][4];
    #pragma unroll
    for (int mf = 0; mf < 4; ++mf)
        #pragma unroll
        for (int nf = 0; nf < 4; ++nf) acc[mf][nf] = (f32x4){0.f, 0.f, 0.f, 0.f};

    for (int kt = 0; kt < DM / 64; ++kt) {
        const int k0 = kt * 64;
        __syncthreads();
        #pragma unroll
        for (int i = 0; i < 4; ++i) {
            async_copy16((char*)Alds + (i * 256 + w * 64) * 16,
                         Ag + (size_t)srow[i] * DM + k0 + scol[i]);
            async_copy16((char*)Blds + (i * 256 + w * 64) * 16,
                         Bg + (size_t)srow[i] * DM + k0 + scol[i]);
        }
        __syncthreads();
        #pragma unroll
        for (int kh = 0; kh < 2; ++kh) {
            half8 af[4], bf[4];
            const int ag = kh * 4 + lrow;
            #pragma unroll
            for (int f = 0; f < 4; ++f) {
                const int ar = wr * 64 + f * 16 + lcol;
                af[f] = *(const half8*)((const char*)Alds +
                          ar * 128 + ((ag ^ (ar & 7)) << 4));
                const int br = wc * 64 + f * 16 + lcol;
                bf[f] = *(const half8*)((const char*)Blds +
                          br * 128 + ((ag ^ (br & 7)) << 4));
            }
            #pragma unroll
            for (int mf = 0; mf < 4; ++mf)
                #pragma unroll
                for (int nf = 0; nf < 4; ++nf)
                    acc[mf][nf] = __builtin_amdgcn_mfma_f32_16x16x32_f16(
                        af[mf], bf[nf], acc[mf][nf], 0, 0, 0);
        }
    }

    #pragma unroll
    for (int nf = 0; nf < 4; ++nf) {
        const int n = cbn * 128 + wc * 64 + nf * 16 + lcol;
        const float b = bias[n];
        #pragma unroll
        for (int mf = 0; mf < 4; ++mf) {
            const int t0 = rbn * 128 + wr * 64 + mf * 16 + lrow * 4;
            #pragma unroll
            for (int r = 0; r < 4; ++r)
                out[(size_t)(t0 + r) * DM + n] = acc[mf][nf][r] + b;
        }
    }
}

// ---------------------------------------------------------------------------
// V [h][t][d] -> Vt [h][d][t] (fp16)
// ---------------------------------------------------------------------------
__global__ __launch_bounds__(256)
void vt_kernel(const _Float16* __restrict__ v, _Float16* __restrict__ vt) {
    __shared__ _Float16 tile[64][65];
    const int tid = threadIdx.x;
    const int tb = blockIdx.x, h = blockIdx.y;
    const int r = tid >> 2, c0 = (tid & 3) * 16;
    const _Float16* src = v + ((size_t)h * T_SEQ + tb * 64 + r) * 64 + c0;
    half8 a0 = *(const half8*)(src);
    half8 a1 = *(const half8*)(src + 8);
    #pragma unroll
    for (int j = 0; j < 8; ++j) tile[r][c0 + j] = a0[j];
    #pragma unroll
    for (int j = 0; j < 8; ++j) tile[r][c0 + 8 + j] = a1[j];
    __syncthreads();
    const int d = tid >> 2, t0 = (tid & 3) * 16;
    half8 o0, o1;
    #pragma unroll
    for (int j = 0; j < 8; ++j) o0[j] = tile[t0 + j][d];
    #pragma unroll
    for (int j = 0; j < 8; ++j) o1[j] = tile[t0 + 8 + j][d];
    _Float16* dst = vt + ((size_t)h * 64 + d) * T_SEQ + tb * 64 + t0;
    *(half8*)(dst) = o0;
    *(half8*)(dst + 8) = o1;
}

// ---------------------------------------------------------------------------
// Flash attention, round 11: SPLIT-KV for TLP. The wave count was pinned at
// 1536 (1.5/SIMD) by the (head, chunk) decomposition — every memory-path
// rewrite (rounds 6-10) was neutral because latency had nothing to overlap
// with. Now: block = (head, 4-chunk group, 16-tile KV segment) -> 960 blocks
// = 3840 waves (3.75/SIMD), max 16 serial tiles per wave (was 64). Each wave
// writes a partial {O/l fp16, m, l f32}; attn_combine merges <=4 partials.
// Segment geometry: group j has ntiles=2j+2, nseg=ceil(ntiles/16); every
// wave is active in every segment (16s <= 2j < niter_w). LDS staging and
// compute body unchanged from round 10.
// ---------------------------------------------------------------------------
__global__ __launch_bounds__(256)
void attn_tile_kernel(const _Float16* __restrict__ qg,
                      const _Float16* __restrict__ kg,
                      const _Float16* __restrict__ vtg,
                      _Float16* __restrict__ pO,
                      float* __restrict__ pml) {
    __shared__ _Float16 Kl[2][4096];   // 2 x 8KB, swizzled [kv][d]
    __shared__ _Float16 Vl[2][4096];   // 2 x 8KB, swizzled [d][kv]

    const int tid  = threadIdx.x;
    const int lane = tid & 63;
    const int w    = tid >> 6;
    const int l31  = lane & 31;
    const int hi   = lane >> 5;

    // block -> (head, group j, segment); heavy (large j) first
    const int b = blockIdx.x;          // 960
    const int h = b % NH;
    const int i = 79 - b / NH;         // 0..79
    int j, seg;
    if (i < 8)       { j = i;                  seg = 0; }
    else if (i < 24) { const int t = i - 8;    j = 8  + (t >> 1); seg = t & 1; }
    else if (i < 48) { const int t = i - 24;   j = 16 + t / 3;    seg = t % 3; }
    else             { const int t = i - 48;   j = 24 + (t >> 2); seg = t & 3; }

    const int cw      = 4 * j + w;          // this wave's q-chunk (per head)
    const int q       = cw * 32 + l31;      // this lane's q-row
    const int niter_w = 2 * j + 1 + (w >> 1);
    const int tS      = seg * 16;
    const int tEndBlk = min(tS + 16, 2 * j + 2);
    const int tEndW   = min(tS + 16, niter_w);

    const _Float16* Qh = qg  + ((size_t)h * T_SEQ + q) * DH;
    const _Float16* Kh = kg  + (size_t)h * T_SEQ * DH;
    const _Float16* Vh = vtg + (size_t)h * DH * T_SEQ;

    // Q fragments (B operand): col=lane&31=q, k(d) = 16*ks + hi*8 + jj
    half8 qf[4];
    #pragma unroll
    for (int ks = 0; ks < 4; ++ks)
        qf[ks] = *(const half8*)(Qh + ks * 16 + hi * 8);

    f32x16 o0v = {}, o1v = {};           // O^T d-tiles 0..31, 32..63
    float m = -1e30f, l = 0.f;

    // staging: 512 granules x 16B per tile, 2 per thread; source pre-swizzled
    const int g0 = tid, g1 = tid + 256;
    const int r0 = g0 >> 3, s0 = ((g0 & 7) ^ (r0 & 7)) * 8;
    const int r1 = g1 >> 3, s1 = ((g1 & 7) ^ (r1 & 7)) * 8;

    auto stage = [&](int p, int kvb) {
        async_copy16((char*)Kl[p] + g0 * 16, Kh + (size_t)(kvb + r0) * DH + s0);
        async_copy16((char*)Kl[p] + g1 * 16, Kh + (size_t)(kvb + r1) * DH + s1);
        async_copy16((char*)Vl[p] + g0 * 16, Vh + (size_t)r0 * T_SEQ + kvb + s0);
        async_copy16((char*)Vl[p] + g1 * 16, Vh + (size_t)r1 * T_SEQ + kvb + s1);
    };

    stage(0, tS * 64);
    for (int it = tS; it < tEndBlk; ++it) {
        const int p = (it - tS) & 1;
        __syncthreads();   // staged tile 'it' visible; prior buffer reads done
        if (it + 1 < tEndBlk) stage(p ^ 1, (it + 1) * 64);
        if (it >= tEndW) continue;      // inactive wave still hits barrier

        const int kvb = it * 64;
        const char* Kb = (const char*)Kl[p];
        const char* Vb = (const char*)Vl[p];
        const int sw7 = l31 & 7;

        // ---- fragments from LDS (swizzled ds_read_b128)
        half8 kfA[4], kfB[4];
        #pragma unroll
        for (int ks = 0; ks < 4; ++ks) {
            const int gsl = (ks * 2 + hi) ^ sw7;
            kfA[ks] = *(const half8*)(Kb + l31 * 128 + (gsl << 4));
            kfB[ks] = *(const half8*)(Kb + (32 + l31) * 128 + (gsl << 4));
        }
        half8 vf[2][2][2];   // [kv-tile][dt][ks2]
        #pragma unroll
        for (int t = 0; t < 2; ++t)
            #pragma unroll
            for (int dt = 0; dt < 2; ++dt)
                #pragma unroll
                for (int ks2 = 0; ks2 < 2; ++ks2) {
                    const int gsl = (t * 4 + ks2 * 2 + hi) ^ sw7;
                    vf[t][dt][ks2] = *(const half8*)(Vb +
                        (dt * 32 + l31) * 128 + (gsl << 4));
                }

        // ---- S^T = K Q^T
        f32x16 sA = {}, sB = {};
        __builtin_amdgcn_s_setprio(1);
        #pragma unroll
        for (int ks = 0; ks < 4; ++ks) {
            sA = __builtin_amdgcn_mfma_f32_32x32x16_f16(kfA[ks], qf[ks], sA, 0, 0, 0);
            sB = __builtin_amdgcn_mfma_f32_32x32x16_f16(kfB[ks], qf[ks], sB, 0, 0, 0);
        }
        __builtin_amdgcn_s_setprio(0);

        // ---- causal mask (diagonal tile of this wave's chunk)
        if (it == niter_w - 1) {
            #pragma unroll
            for (int r = 0; r < 16; ++r) {
                const int off = (r & 3) + 8 * (r >> 2) + 4 * hi;
                if (kvb + off > q)      sA[r] = -1e30f;
                if (kvb + 32 + off > q) sB[r] = -1e30f;
            }
        }

        // ---- online softmax (exp2 domain): tree max, permlane cross-half
        float t8[8];
        #pragma unroll
        for (int r = 0; r < 8; ++r)
            t8[r] = fmaxf(fmaxf(sA[r], sA[r + 8]), fmaxf(sB[r], sB[r + 8]));
        float t4a = fmaxf(t8[0], t8[4]), t4b = fmaxf(t8[1], t8[5]);
        float t4c = fmaxf(t8[2], t8[6]), t4d = fmaxf(t8[3], t8[7]);
        float pmax = fmaxf(fmaxf(t4a, t4b), fmaxf(t4c, t4d));
        {
            auto r = __builtin_amdgcn_permlane32_swap(asu(pmax), asu(pmax), false, false);
            pmax = fmaxf(asf(r[0]), asf(r[1]));
        }

        if (!__all(pmax - m <= 11.0f)) {   // defer-max
            const float mnew = fmaxf(m, pmax);
            const float alpha = exp2f(m - mnew);
            m = mnew;
            l *= alpha;
            #pragma unroll
            for (int r = 0; r < 16; ++r) { o0v[r] *= alpha; o1v[r] *= alpha; }
        }
        #pragma unroll
        for (int r = 0; r < 16; ++r) sA[r] = exp2f(sA[r] - m);
        #pragma unroll
        for (int r = 0; r < 16; ++r) sB[r] = exp2f(sB[r] - m);
        float s8[8];
        #pragma unroll
        for (int r = 0; r < 8; ++r)
            s8[r] = (sA[r] + sA[r + 8]) + (sB[r] + sB[r + 8]);
        float rsum = ((s8[0] + s8[4]) + (s8[1] + s8[5])) +
                     ((s8[2] + s8[6]) + (s8[3] + s8[7]));
        {
            auto r = __builtin_amdgcn_permlane32_swap(asu(rsum), asu(rsum), false, false);
            rsum = asf(r[0]) + asf(r[1]);
        }
        l += rsum;

        // ---- pack P -> PV B-frags: 4 cvt_pkrtz + 2 permlane per group
        H8 pfA[2], pfB[2];
        #pragma unroll
        for (int ks2 = 0; ks2 < 2; ++ks2) {
            {
                const u32 a0 = pkrtz_u32(sA[8*ks2+0], sA[8*ks2+1]);
                const u32 a1 = pkrtz_u32(sA[8*ks2+2], sA[8*ks2+3]);
                const u32 b0 = pkrtz_u32(sA[8*ks2+4], sA[8*ks2+5]);
                const u32 b1 = pkrtz_u32(sA[8*ks2+6], sA[8*ks2+7]);
                auto r0 = __builtin_amdgcn_permlane32_swap(a0, b0, false, false);
                auto r1 = __builtin_amdgcn_permlane32_swap(a1, b1, false, false);
                pfA[ks2].u[0] = r0[0];
                pfA[ks2].u[1] = r1[0];
                pfA[ks2].u[2] = r0[1];
                pfA[ks2].u[3] = r1[1];
            }
            {
                const u32 a0 = pkrtz_u32(sB[8*ks2+0], sB[8*ks2+1]);
                const u32 a1 = pkrtz_u32(sB[8*ks2+2], sB[8*ks2+3]);
                const u32 b0 = pkrtz_u32(sB[8*ks2+4], sB[8*ks2+5]);
                const u32 b1 = pkrtz_u32(sB[8*ks2+6], sB[8*ks2+7]);
                auto r0 = __builtin_amdgcn_permlane32_swap(a0, b0, false, false);
                auto r1 = __builtin_amdgcn_permlane32_swap(a1, b1, false, false);
                pfB[ks2].u[0] = r0[0];
                pfB[ks2].u[1] = r1[0];
                pfB[ks2].u[2] = r0[1];
                pfB[ks2].u[3] = r1[1];
            }
        }

        // ---- PV: O^T[d][q] += V^T · P̂
        __builtin_amdgcn_s_setprio(1);
        #pragma unroll
        for (int ks2 = 0; ks2 < 2; ++ks2) {
            o0v = __builtin_amdgcn_mfma_f32_32x32x16_f16(vf[0][0][ks2], pfA[ks2].v, o0v, 0, 0, 0);
            o1v = __builtin_amdgcn_mfma_f32_32x32x16_f16(vf[0][1][ks2], pfA[ks2].v, o1v, 0, 0, 0);
            o0v = __builtin_amdgcn_mfma_f32_32x32x16_f16(vf[1][0][ks2], pfB[ks2].v, o0v, 0, 0, 0);
            o1v = __builtin_amdgcn_mfma_f32_32x32x16_f16(vf[1][1][ks2], pfB[ks2].v, o1v, 0, 0, 0);
        }
        __builtin_amdgcn_s_setprio(0);
    }

    // ---- epilogue: write partial {O/l fp16, m, l f32} for (chunk, seg)
    const int hc = h * 128 + cw;
    const float inv = (l > 0.f) ? 1.0f / l : 0.f;
    _Float16* op = pO + ((size_t)(seg * 1536 + hc) * 32 + l31) * 64 + 4 * hi;
    #pragma unroll
    for (int g = 0; g < 4; ++g) {
        half4v w0 = { (_Float16)(o0v[4*g+0] * inv), (_Float16)(o0v[4*g+1] * inv),
                      (_Float16)(o0v[4*g+2] * inv), (_Float16)(o0v[4*g+3] * inv) };
        half4v w1 = { (_Float16)(o1v[4*g+0] * inv), (_Float16)(o1v[4*g+1] * inv),
                      (_Float16)(o1v[4*g+2] * inv), (_Float16)(o1v[4*g+3] * inv) };
        *(half4v*)(op + 8 * g)      = w0;
        *(half4v*)(op + 32 + 8 * g) = w1;
    }
    if (hi == 0) {
        float* mp = pml + ((size_t)(seg * 1536 + hc) * 32 + l31) * 2;
        mp[0] = m;
        mp[1] = l;
    }
}

// ---------------------------------------------------------------------------
// Combine <=4 partials per q-row: O = sum_i (l_i 2^{m_i-M} / L) * (O_i/l_i)
// ---------------------------------------------------------------------------
__global__ __launch_bounds__(256)
void attn_combine_kernel(const _Float16* __restrict__ pO,
                         const float* __restrict__ pml,
                         _Float16* __restrict__ att) {
    const int row = blockIdx.x * 256 + threadIdx.x;   // 49152 rows
    const int q5 = row & 31;
    const int hc = row >> 5;          // h*128 + c
    const int c  = hc & 127;
    const int h  = hc >> 7;
    const int nseg = 1 + (c >= 32) + (c >= 64) + (c >= 96);

    float mm[4], ll[4];
    float M = -1e30f;
    #pragma unroll
    for (int s = 0; s < 4; ++s) {
        const bool on = s < nseg;
        const float* mp = pml + ((size_t)(s * 1536 + hc) * 32 + q5) * 2;
        mm[s] = on ? mp[0] : -1e30f;
        ll[s] = on ? mp[1] : 0.f;
        M = fmaxf(M, mm[s]);
    }
    float wgt[4];
    float L = 0.f;
    #pragma unroll
    for (int s = 0; s < 4; ++s) {
        wgt[s] = ll[s] * exp2f(mm[s] - M);
        L += wgt[s];
    }
    const float invL = 1.0f / L;
    #pragma unroll
    for (int s = 0; s < 4; ++s) wgt[s] *= invL;

    float acc[64];
    #pragma unroll
    for (int d = 0; d < 64; ++d) acc[d] = 0.f;
    #pragma unroll
    for (int s = 0; s < 4; ++s) {
        if (s >= nseg) break;
        const _Float16* src = pO + ((size_t)(s * 1536 + hc) * 32 + q5) * 64;
        const float wsc = wgt[s];
        #pragma unroll
        for (int g = 0; g < 8; ++g) {
            half8 v = *(const half8*)(src + g * 8);
            #pragma unroll
            for (int jj = 0; jj < 8; ++jj)
                acc[g * 8 + jj] += wsc * (float)v[jj];
        }
    }
    _Float16* dst = att + (size_t)(c * 32 + q5) * DM + h * DH;
    #pragma unroll
    for (int g = 0; g < 8; ++g) {
        half8 o;
        #pragma unroll
        for (int jj = 0; jj < 8; ++jj) o[jj] = (_Float16)acc[g * 8 + jj];
        *(half8*)(dst + g * 8) = o;
    }
}

// ---------------------------------------------------------------------------
extern "C" void kernel_launch(void* const* d_in, const int* in_sizes, int n_in,
                              void* d_out, int out_size, void* d_ws, size_t ws_size,
                              hipStream_t stream) {
    const float* x      = (const float*)d_in[0];
    const float* w_qkv  = (const float*)d_in[1];
    const float* w_proj = (const float*)d_in[2];
    const float* b_proj = (const float*)d_in[3];
    float* out = (float*)d_out;

    _Float16* wsb = (_Float16*)d_ws;
    const size_t XS = (size_t)T_SEQ * DM;
    const size_t HS = (size_t)NH * T_SEQ * DH;
    _Float16* xh     = wsb;
    _Float16* wqkvT  = xh + XS;
    _Float16* wprojT = wqkvT + (size_t)NC * DM;
    _Float16* q      = wprojT + (size_t)DM * DM;
    _Float16* k      = q + HS;
    _Float16* v      = k + HS;
    _Float16* vt     = v + HS;
    _Float16* att    = vt + HS;
    _Float16* pO     = att + XS;                       // 4*1536*32*64 fp16
    float*    pml    = (float*)(pO + (size_t)4 * 1536 * 32 * 64);

    convert_x_kernel<<<dim3(1536), 256, 0, stream>>>(x, xh);
    transpose_convert_kernel<<<dim3(36, 12), 256, 0, stream>>>(w_qkv, wqkvT, DM, NC);
    transpose_convert_kernel<<<dim3(12, 12), 256, 0, stream>>>(w_proj, wprojT, DM, DM);
    qkv_mfma_kernel<<<dim3(576), 256, 0, stream>>>(xh, wqkvT, q, k, v);
    vt_kernel<<<dim3(64, NH), 256, 0, stream>>>(v, vt);
    attn_tile_kernel<<<dim3(960), 256, 0, stream>>>(q, k, vt, pO, pml);
    attn_combine_kernel<<<dim3(192), 256, 0, stream>>>(pO, pml, att);
    proj_mfma_kernel<<<dim3(192), 256, 0, stream>>>(att, wprojT, b_proj, out);
}